// Round 7
// baseline (351.539 us; speedup 1.0000x reference)
//
#include <hip/hip_runtime.h>

#define N_USERS 100000
#define N_ITEMS 50000
#define N_NODES 150000
#define DIM 64
#define NNZ_C 2400000
#define BATCH 16384

#define BUCKROWS 1024
#define NBUCK ((N_NODES + BUCKROWS - 1) / BUCKROWS)   // 147 buckets of 1024 rows
#define CHUNK 8192
#define NCHUNK ((NNZ_C + CHUNK - 1) / CHUNK)          // 293 chunks

typedef float f32x4 __attribute__((ext_vector_type(4)));

// ---- k1: per-chunk LDS histogram over 147 buckets -------------------------
__global__ void k1_hist(const int* __restrict__ rows, int* __restrict__ ghist) {
    __shared__ int hist[NBUCK];
    int blk = blockIdx.x, tid = threadIdx.x;
    for (int b = tid; b < NBUCK; b += 256) hist[b] = 0;
    __syncthreads();
    int base = blk * CHUNK;
    int end = min(base + CHUNK, NNZ_C);
    for (int e = base + tid; e < end; e += 256)
        atomicAdd(&hist[rows[e] >> 10], 1);           // LDS atomic
    __syncthreads();
    for (int b = tid; b < NBUCK; b += 256)
        ghist[(size_t)b * NCHUNK + blk] = hist[b];
}

// ---- k2a: per-bucket exclusive scan over NCHUNK (293) entries --------------
__global__ void k2a_scan_chunks(int* __restrict__ ghist, int* __restrict__ btot) {
    __shared__ int s[512];
    int b = blockIdx.x, t = threadIdx.x;
    int v = (t < NCHUNK) ? ghist[(size_t)b * NCHUNK + t] : 0;
    s[t] = v;
    __syncthreads();
    for (int off = 1; off < 512; off <<= 1) {
        int u = (t >= off) ? s[t - off] : 0;
        __syncthreads();
        s[t] += u;
        __syncthreads();
    }
    if (t < NCHUNK) ghist[(size_t)b * NCHUNK + t] = s[t] - v;
    if (t == NCHUNK - 1) btot[b] = s[t];
}

// ---- k2b: exclusive scan of 147 bucket totals ------------------------------
__global__ void k2b_scan_buckets(const int* __restrict__ btot, int* __restrict__ bbase,
                                 int* __restrict__ rowptr) {
    __shared__ int s[256];
    int t = threadIdx.x;
    int v = (t < NBUCK) ? btot[t] : 0;
    s[t] = v;
    __syncthreads();
    for (int off = 1; off < 256; off <<= 1) {
        int u = (t >= off) ? s[t - off] : 0;
        __syncthreads();
        s[t] += u;
        __syncthreads();
    }
    if (t < NBUCK) bbase[t] = s[t] - v;
    if (t == 255) { bbase[NBUCK] = s[255]; rowptr[N_NODES] = NNZ_C; }
}

// ---- k3: scatter edges into bucket-grouped order (LDS cursors) ------------
__global__ void k3_scatter(const int* __restrict__ rows, const int* __restrict__ cols,
                           const float* __restrict__ vals,
                           const int* __restrict__ ghist, const int* __restrict__ bbase,
                           int2* __restrict__ cv_tmp, unsigned short* __restrict__ rl_tmp) {
    __shared__ int cur[NBUCK];
    int blk = blockIdx.x, tid = threadIdx.x;
    for (int b = tid; b < NBUCK; b += 256)
        cur[b] = bbase[b] + ghist[(size_t)b * NCHUNK + blk];
    __syncthreads();
    int base = blk * CHUNK;
    int end = min(base + CHUNK, NNZ_C);
    for (int e = base + tid; e < end; e += 256) {
        int r = rows[e];
        int pos = atomicAdd(&cur[r >> 10], 1);        // LDS atomic
        int2 cv;
        cv.x = cols[e];
        cv.y = __float_as_int(vals[e]);
        cv_tmp[pos] = cv;
        rl_tmp[pos] = (unsigned short)(r & 1023);
    }
}

// ---- k4: sort 1024 row-locals within each contiguous bucket window --------
__global__ void k4_sort(const int* __restrict__ bbase,
                        const int2* __restrict__ cv_in,
                        const unsigned short* __restrict__ rl_in,
                        int* __restrict__ rowptr, int2* __restrict__ cv_out) {
    __shared__ int hist[BUCKROWS];      // reused as cursors
    __shared__ int part[256];
    int b = blockIdx.x, tid = threadIdx.x;
    int base = bbase[b];
    int cnt = bbase[b + 1] - base;
    for (int i = tid; i < BUCKROWS; i += 256) hist[i] = 0;
    __syncthreads();
    for (int i = tid; i < cnt; i += 256)
        atomicAdd(&hist[rl_in[base + i]], 1);
    __syncthreads();
    int h0 = hist[4 * tid], h1 = hist[4 * tid + 1];
    int h2 = hist[4 * tid + 2], h3 = hist[4 * tid + 3];
    int sum4 = h0 + h1 + h2 + h3;
    part[tid] = sum4;
    __syncthreads();
    for (int off = 1; off < 256; off <<= 1) {
        int u = (tid >= off) ? part[tid - off] : 0;
        __syncthreads();
        part[tid] += u;
        __syncthreads();
    }
    int excl = part[tid] - sum4;
    hist[4 * tid]     = excl;
    hist[4 * tid + 1] = excl + h0;
    hist[4 * tid + 2] = excl + h0 + h1;
    hist[4 * tid + 3] = excl + h0 + h1 + h2;
    __syncthreads();
    int rowbase = b * BUCKROWS;
    for (int i = tid; i < BUCKROWS; i += 256) {
        int g = rowbase + i;
        if (g < N_NODES) rowptr[g] = base + hist[i];
    }
    __syncthreads();
    for (int i = tid; i < cnt; i += 256) {
        int rl = rl_in[base + i];
        int pos = atomicAdd(&hist[rl], 1);            // LDS cursor
        cv_out[base + pos] = cv_in[base + i];         // write within 128KB window
    }
}

// ---- SpMM: one wave per row; 16 lanes x float4, 4 edges in flight ---------
__global__ void spmm_rows(const int* __restrict__ rowptr, const int2* __restrict__ cv,
                          const float* __restrict__ E, float* __restrict__ Eout) {
    int t = blockIdx.x * blockDim.x + threadIdx.x;
    int row = t >> 6;
    if (row >= N_NODES) return;
    int lane = t & 63;
    int g = lane >> 4, q = lane & 15;
    int ru = __builtin_amdgcn_readfirstlane(row);
    int start = rowptr[ru], end = rowptr[ru + 1];
    float ax = 0.f, ay = 0.f, az = 0.f, aw = 0.f;
    for (int j = start; j < end; j += 4) {
        int jj = j + g;
        int2 c = cv[jj];                              // buffer padded past NNZ
        bool ok = jj < end;
        float v = ok ? __int_as_float(c.y) : 0.f;
        int col = ok ? c.x : 0;
        float4 x = ((const float4*)(E + (size_t)col * DIM))[q];
        ax += v * x.x; ay += v * x.y; az += v * x.z; aw += v * x.w;
    }
    ax += __shfl_xor(ax, 16, 64); ay += __shfl_xor(ay, 16, 64);
    az += __shfl_xor(az, 16, 64); aw += __shfl_xor(aw, 16, 64);
    ax += __shfl_xor(ax, 32, 64); ay += __shfl_xor(ay, 32, 64);
    az += __shfl_xor(az, 32, 64); aw += __shfl_xor(aw, 32, 64);
    if (g == 0) {
        f32x4 o;
        o.x = ax; o.y = ay; o.z = az; o.w = aw;
        __builtin_nontemporal_store(o, (f32x4*)(Eout + (size_t)row * DIM) + q);
    }
}

// ---- batch init / accumulate -----------------------------------------------
__global__ void batch_init(const float* __restrict__ E, const int* __restrict__ U,
                           const int* __restrict__ I,
                           float* __restrict__ accU, float* __restrict__ accI) {
    int t = blockIdx.x * blockDim.x + threadIdx.x;
    int b = t >> 6, lane = t & 63;
    if (b >= BATCH) return;
    int bu = __builtin_amdgcn_readfirstlane(b);
    int u = U[bu], it = I[bu];
    accU[(size_t)b * DIM + lane] = E[(size_t)u * DIM + lane];
    accI[(size_t)b * DIM + lane] = E[(size_t)(N_USERS + it) * DIM + lane];
}

__global__ void batch_acc(const float* __restrict__ E, const int* __restrict__ U,
                          const int* __restrict__ I,
                          float* __restrict__ accU, float* __restrict__ accI) {
    int t = blockIdx.x * blockDim.x + threadIdx.x;
    int b = t >> 6, lane = t & 63;
    if (b >= BATCH) return;
    int bu = __builtin_amdgcn_readfirstlane(b);
    int u = U[bu], it = I[bu];
    accU[(size_t)b * DIM + lane] += E[(size_t)u * DIM + lane];
    accI[(size_t)b * DIM + lane] += E[(size_t)(N_USERS + it) * DIM + lane];
}

// ---- partial layer-3: compute A*E rows only for batch nodes ----------------
__global__ void partial3(const int* __restrict__ rowptr, const int2* __restrict__ cv,
                         const float* __restrict__ E,
                         const int* __restrict__ U, const int* __restrict__ I,
                         float* __restrict__ accU, float* __restrict__ accI) {
    int t = blockIdx.x * blockDim.x + threadIdx.x;
    int s = t >> 6;
    if (s >= 2 * BATCH) return;
    int lane = t & 63;
    int g = lane >> 4, q = lane & 15;
    int su = __builtin_amdgcn_readfirstlane(s);
    int row;
    float* acc;
    if (su < BATCH) {
        row = U[su];
        acc = accU + (size_t)su * DIM;
    } else {
        row = N_USERS + I[su - BATCH];
        acc = accI + (size_t)(su - BATCH) * DIM;
    }
    int start = rowptr[row], end = rowptr[row + 1];
    float ax = 0.f, ay = 0.f, az = 0.f, aw = 0.f;
    for (int j = start; j < end; j += 4) {
        int jj = j + g;
        int2 c = cv[jj];
        bool ok = jj < end;
        float v = ok ? __int_as_float(c.y) : 0.f;
        int col = ok ? c.x : 0;
        float4 x = ((const float4*)(E + (size_t)col * DIM))[q];
        ax += v * x.x; ay += v * x.y; az += v * x.z; aw += v * x.w;
    }
    ax += __shfl_xor(ax, 16, 64); ay += __shfl_xor(ay, 16, 64);
    az += __shfl_xor(az, 16, 64); aw += __shfl_xor(aw, 16, 64);
    ax += __shfl_xor(ax, 32, 64); ay += __shfl_xor(ay, 32, 64);
    az += __shfl_xor(az, 32, 64); aw += __shfl_xor(aw, 32, 64);
    if (g == 0) {
        float4 p = ((float4*)acc)[q];
        p.x += ax; p.y += ay; p.z += az; p.w += aw;
        ((float4*)acc)[q] = p;
    }
}

// ---- final dot, scale 1/16 --------------------------------------------------
__global__ void dot_out(const float* __restrict__ accU, const float* __restrict__ accI,
                        float* __restrict__ out) {
    int t = blockIdx.x * blockDim.x + threadIdx.x;
    int b = t >> 6, lane = t & 63;
    if (b >= BATCH) return;
    float p = accU[(size_t)b * DIM + lane] * accI[(size_t)b * DIM + lane];
    #pragma unroll
    for (int off = 32; off; off >>= 1) p += __shfl_xor(p, off, 64);
    if (lane == 0) out[b] = p * (1.0f / 16.0f);
}

extern "C" void kernel_launch(void* const* d_in, const int* in_sizes, int n_in,
                              void* d_out, int out_size, void* d_ws, size_t ws_size,
                              hipStream_t stream) {
    const float* emb   = (const float*)d_in[0];
    const int*   Arows = (const int*)d_in[1];
    const int*   Acols = (const int*)d_in[2];
    const float* Avals = (const float*)d_in[3];
    const int*   U     = (const int*)d_in[4];
    const int*   I     = (const int*)d_in[5];
    float* out = (float*)d_out;

    char* ws = (char*)d_ws;
    size_t off = 0;
    auto alloc = [&](size_t bytes) {
        char* p = ws + off;
        off += (bytes + 255) & ~(size_t)255;
        return p;
    };
    float* e0     = (float*)alloc((size_t)N_NODES * DIM * 4);      // 38.4 MB
    float* e1     = (float*)alloc((size_t)N_NODES * DIM * 4);      // 38.4 MB
    int2*  colval = (int2*) alloc(((size_t)NNZ_C + 64) * 8);       // 19.2 MB (row-sorted)
    float* accU   = (float*)alloc((size_t)BATCH * DIM * 4);        // 4.2 MB
    float* accI   = (float*)alloc((size_t)BATCH * DIM * 4);        // 4.2 MB
    int*   rowptr = (int*)  alloc((size_t)(N_NODES + 1) * 4);      // 0.6 MB

    // Build temporaries aliased into e0/e1 (dead before the layers write them)
    int2*           cv_tmp = (int2*)e0;                            // 19.2 MB in e0
    char*           e1c    = (char*)e1;
    unsigned short* rl_tmp = (unsigned short*)e1c;                 // 4.8 MB
    int*            ghist  = (int*)(e1c + (((size_t)NNZ_C * 2 + 255) & ~(size_t)255)); // 172 KB
    int*            btot   = ghist + (size_t)NBUCK * NCHUNK;
    int*            bbase  = btot + NBUCK;                         // NBUCK+1 ints

    // ---- build: chunk histogram -> scans -> bucket scatter -> row sort ----
    k1_hist<<<NCHUNK, 256, 0, stream>>>(Arows, ghist);
    k2a_scan_chunks<<<NBUCK, 512, 0, stream>>>(ghist, btot);
    k2b_scan_buckets<<<1, 256, 0, stream>>>(btot, bbase, rowptr);
    k3_scatter<<<NCHUNK, 256, 0, stream>>>(Arows, Acols, Avals, ghist, bbase,
                                           cv_tmp, rl_tmp);
    k4_sort<<<NBUCK, 256, 0, stream>>>(bbase, cv_tmp, rl_tmp, rowptr, colval);

    int spmm_blocks = (N_NODES * 64 + 255) / 256;
    int bacc_blocks = (BATCH * 64 + 255) / 256;
    int p3_blocks   = (2 * BATCH * 64 + 255) / 256;

    // layer 0
    batch_init<<<bacc_blocks, 256, 0, stream>>>(emb, U, I, accU, accI);
    // layer 1: emb -> e0 (cv_tmp dead from here on)
    spmm_rows<<<spmm_blocks, 256, 0, stream>>>(rowptr, colval, emb, e0);
    batch_acc<<<bacc_blocks, 256, 0, stream>>>(e0, U, I, accU, accI);
    // layer 2: e0 -> e1 (rl_tmp/ghist/btot/bbase dead from here on)
    spmm_rows<<<spmm_blocks, 256, 0, stream>>>(rowptr, colval, e0, e1);
    batch_acc<<<bacc_blocks, 256, 0, stream>>>(e1, U, I, accU, accI);
    // layer 3: only the 2*BATCH rows the output needs
    partial3<<<p3_blocks, 256, 0, stream>>>(rowptr, colval, e1, U, I, accU, accI);
    dot_out<<<bacc_blocks, 256, 0, stream>>>(accU, accI, out);
}

// Round 8
// 326.087 us; speedup vs baseline: 1.0781x; 1.0781x over previous
//
#include <hip/hip_runtime.h>

#define N_USERS 100000
#define N_ITEMS 50000
#define N_NODES 150000
#define DIM 64
#define NNZ_C 2400000
#define BATCH 16384

#define BUCKROWS 1024
#define NBUCK ((N_NODES + BUCKROWS - 1) / BUCKROWS)   // 147 buckets of 1024 rows
#define CHUNK 8192
#define NCHUNK ((NNZ_C + CHUNK - 1) / CHUNK)          // 293 chunks

// ---- k1: per-chunk LDS histogram over 147 buckets -------------------------
__global__ void k1_hist(const int* __restrict__ rows, int* __restrict__ ghist) {
    __shared__ int hist[NBUCK];
    int blk = blockIdx.x, tid = threadIdx.x;
    for (int b = tid; b < NBUCK; b += 256) hist[b] = 0;
    __syncthreads();
    int base = blk * CHUNK;
    int end = min(base + CHUNK, NNZ_C);
    for (int e = base + tid; e < end; e += 256)
        atomicAdd(&hist[rows[e] >> 10], 1);           // LDS atomic
    __syncthreads();
    for (int b = tid; b < NBUCK; b += 256)
        ghist[(size_t)b * NCHUNK + blk] = hist[b];
}

// ---- k2a: per-bucket exclusive scan over NCHUNK (293) entries --------------
__global__ void k2a_scan_chunks(int* __restrict__ ghist, int* __restrict__ btot) {
    __shared__ int s[512];
    int b = blockIdx.x, t = threadIdx.x;
    int v = (t < NCHUNK) ? ghist[(size_t)b * NCHUNK + t] : 0;
    s[t] = v;
    __syncthreads();
    for (int off = 1; off < 512; off <<= 1) {
        int u = (t >= off) ? s[t - off] : 0;
        __syncthreads();
        s[t] += u;
        __syncthreads();
    }
    if (t < NCHUNK) ghist[(size_t)b * NCHUNK + t] = s[t] - v;
    if (t == NCHUNK - 1) btot[b] = s[t];
}

// ---- k2b: exclusive scan of 147 bucket totals ------------------------------
__global__ void k2b_scan_buckets(const int* __restrict__ btot, int* __restrict__ bbase,
                                 int* __restrict__ rowptr) {
    __shared__ int s[256];
    int t = threadIdx.x;
    int v = (t < NBUCK) ? btot[t] : 0;
    s[t] = v;
    __syncthreads();
    for (int off = 1; off < 256; off <<= 1) {
        int u = (t >= off) ? s[t - off] : 0;
        __syncthreads();
        s[t] += u;
        __syncthreads();
    }
    if (t < NBUCK) bbase[t] = s[t] - v;
    if (t == 255) { bbase[NBUCK] = s[255]; rowptr[N_NODES] = NNZ_C; }
}

// ---- k3: scatter edges into bucket-grouped order (LDS cursors) ------------
__global__ void k3_scatter(const int* __restrict__ rows, const int* __restrict__ cols,
                           const float* __restrict__ vals,
                           const int* __restrict__ ghist, const int* __restrict__ bbase,
                           int2* __restrict__ cv_tmp, unsigned short* __restrict__ rl_tmp) {
    __shared__ int cur[NBUCK];
    int blk = blockIdx.x, tid = threadIdx.x;
    for (int b = tid; b < NBUCK; b += 256)
        cur[b] = bbase[b] + ghist[(size_t)b * NCHUNK + blk];
    __syncthreads();
    int base = blk * CHUNK;
    int end = min(base + CHUNK, NNZ_C);
    for (int e = base + tid; e < end; e += 256) {
        int r = rows[e];
        int pos = atomicAdd(&cur[r >> 10], 1);        // LDS atomic
        int2 cv;
        cv.x = cols[e];
        cv.y = __float_as_int(vals[e]);
        cv_tmp[pos] = cv;
        rl_tmp[pos] = (unsigned short)(r & 1023);
    }
}

// ---- k4: sort 1024 row-locals within each contiguous bucket window --------
__global__ void k4_sort(const int* __restrict__ bbase,
                        const int2* __restrict__ cv_in,
                        const unsigned short* __restrict__ rl_in,
                        int* __restrict__ rowptr, int2* __restrict__ cv_out) {
    __shared__ int hist[BUCKROWS];      // reused as cursors
    __shared__ int part[256];
    int b = blockIdx.x, tid = threadIdx.x;
    int base = bbase[b];
    int cnt = bbase[b + 1] - base;
    for (int i = tid; i < BUCKROWS; i += 256) hist[i] = 0;
    __syncthreads();
    for (int i = tid; i < cnt; i += 256)
        atomicAdd(&hist[rl_in[base + i]], 1);
    __syncthreads();
    int h0 = hist[4 * tid], h1 = hist[4 * tid + 1];
    int h2 = hist[4 * tid + 2], h3 = hist[4 * tid + 3];
    int sum4 = h0 + h1 + h2 + h3;
    part[tid] = sum4;
    __syncthreads();
    for (int off = 1; off < 256; off <<= 1) {
        int u = (tid >= off) ? part[tid - off] : 0;
        __syncthreads();
        part[tid] += u;
        __syncthreads();
    }
    int excl = part[tid] - sum4;
    hist[4 * tid]     = excl;
    hist[4 * tid + 1] = excl + h0;
    hist[4 * tid + 2] = excl + h0 + h1;
    hist[4 * tid + 3] = excl + h0 + h1 + h2;
    __syncthreads();
    int rowbase = b * BUCKROWS;
    for (int i = tid; i < BUCKROWS; i += 256) {
        int g = rowbase + i;
        if (g < N_NODES) rowptr[g] = base + hist[i];
    }
    __syncthreads();
    for (int i = tid; i < cnt; i += 256) {
        int rl = rl_in[base + i];
        int pos = atomicAdd(&hist[rl], 1);            // LDS cursor
        cv_out[base + pos] = cv_in[base + i];         // write within 128KB window
    }
}

// ---- SpMM: one wave per row; colvals staged via shfl; depth-2 pipeline ----
__global__ void spmm_rows(const int* __restrict__ rowptr, const int2* __restrict__ cv,
                          const float* __restrict__ E, float* __restrict__ Eout) {
    int t = blockIdx.x * blockDim.x + threadIdx.x;
    int row = t >> 6;
    if (row >= N_NODES) return;
    int lane = t & 63;
    int g = lane >> 4, q = lane & 15;
    int ru = __builtin_amdgcn_readfirstlane(row);
    int start = rowptr[ru], end = rowptr[ru + 1];
    int len = end - start;
    int nfull = min(len, 64);
    // one coalesced load stages the row's (col,val) pairs across lanes
    int2 mycv = cv[start + (lane < nfull ? lane : 0)];
    float ax = 0.f, ay = 0.f, az = 0.f, aw = 0.f;
    int iters = (nfull + 3) >> 2;                     // wave-uniform
    if (iters > 0) {
        int k = g;
        int sc = __shfl(mycv.x, k, 64);
        int sv = __shfl(mycv.y, k, 64);
        bool ok = k < nfull;
        int col = ok ? sc : 0;
        float v = ok ? __int_as_float(sv) : 0.f;
        float4 x = ((const float4*)(E + (size_t)col * DIM))[q];
        for (int i = 1; i < iters; ++i) {
            int k1 = g + 4 * i;
            int sc1 = __shfl(mycv.x, k1, 64);
            int sv1 = __shfl(mycv.y, k1, 64);
            bool ok1 = k1 < nfull;
            int col1 = ok1 ? sc1 : 0;
            float v1 = ok1 ? __int_as_float(sv1) : 0.f;
            float4 x1 = ((const float4*)(E + (size_t)col1 * DIM))[q];
            ax += v * x.x; ay += v * x.y; az += v * x.z; aw += v * x.w;
            v = v1; x = x1;
        }
        ax += v * x.x; ay += v * x.y; az += v * x.z; aw += v * x.w;
    }
    // rare tail: rows longer than 64 edges
    for (int j = start + 64 + g; j < end; j += 4) {
        int2 c = cv[j];
        float vv = __int_as_float(c.y);
        float4 x = ((const float4*)(E + (size_t)c.x * DIM))[q];
        ax += vv * x.x; ay += vv * x.y; az += vv * x.z; aw += vv * x.w;
    }
    ax += __shfl_xor(ax, 16, 64); ay += __shfl_xor(ay, 16, 64);
    az += __shfl_xor(az, 16, 64); aw += __shfl_xor(aw, 16, 64);
    ax += __shfl_xor(ax, 32, 64); ay += __shfl_xor(ay, 32, 64);
    az += __shfl_xor(az, 32, 64); aw += __shfl_xor(aw, 32, 64);
    if (g == 0) {
        float4 o; o.x = ax; o.y = ay; o.z = az; o.w = aw;
        ((float4*)(Eout + (size_t)row * DIM))[q] = o;
    }
}

// ---- batch init / accumulate -----------------------------------------------
__global__ void batch_init(const float* __restrict__ E, const int* __restrict__ U,
                           const int* __restrict__ I,
                           float* __restrict__ accU, float* __restrict__ accI) {
    int t = blockIdx.x * blockDim.x + threadIdx.x;
    int b = t >> 6, lane = t & 63;
    if (b >= BATCH) return;
    int bu = __builtin_amdgcn_readfirstlane(b);
    int u = U[bu], it = I[bu];
    accU[(size_t)b * DIM + lane] = E[(size_t)u * DIM + lane];
    accI[(size_t)b * DIM + lane] = E[(size_t)(N_USERS + it) * DIM + lane];
}

__global__ void batch_acc(const float* __restrict__ E, const int* __restrict__ U,
                          const int* __restrict__ I,
                          float* __restrict__ accU, float* __restrict__ accI) {
    int t = blockIdx.x * blockDim.x + threadIdx.x;
    int b = t >> 6, lane = t & 63;
    if (b >= BATCH) return;
    int bu = __builtin_amdgcn_readfirstlane(b);
    int u = U[bu], it = I[bu];
    accU[(size_t)b * DIM + lane] += E[(size_t)u * DIM + lane];
    accI[(size_t)b * DIM + lane] += E[(size_t)(N_USERS + it) * DIM + lane];
}

// ---- partial layer-3: only batch rows; same staged/pipelined gather -------
__global__ void partial3(const int* __restrict__ rowptr, const int2* __restrict__ cv,
                         const float* __restrict__ E,
                         const int* __restrict__ U, const int* __restrict__ I,
                         float* __restrict__ accU, float* __restrict__ accI) {
    int t = blockIdx.x * blockDim.x + threadIdx.x;
    int s = t >> 6;
    if (s >= 2 * BATCH) return;
    int lane = t & 63;
    int g = lane >> 4, q = lane & 15;
    int su = __builtin_amdgcn_readfirstlane(s);
    int row;
    float* acc;
    if (su < BATCH) {
        row = U[su];
        acc = accU + (size_t)su * DIM;
    } else {
        row = N_USERS + I[su - BATCH];
        acc = accI + (size_t)(su - BATCH) * DIM;
    }
    int start = rowptr[row], end = rowptr[row + 1];
    int len = end - start;
    int nfull = min(len, 64);
    int2 mycv = cv[start + (lane < nfull ? lane : 0)];
    float ax = 0.f, ay = 0.f, az = 0.f, aw = 0.f;
    int iters = (nfull + 3) >> 2;
    if (iters > 0) {
        int k = g;
        int sc = __shfl(mycv.x, k, 64);
        int sv = __shfl(mycv.y, k, 64);
        bool ok = k < nfull;
        int col = ok ? sc : 0;
        float v = ok ? __int_as_float(sv) : 0.f;
        float4 x = ((const float4*)(E + (size_t)col * DIM))[q];
        for (int i = 1; i < iters; ++i) {
            int k1 = g + 4 * i;
            int sc1 = __shfl(mycv.x, k1, 64);
            int sv1 = __shfl(mycv.y, k1, 64);
            bool ok1 = k1 < nfull;
            int col1 = ok1 ? sc1 : 0;
            float v1 = ok1 ? __int_as_float(sv1) : 0.f;
            float4 x1 = ((const float4*)(E + (size_t)col1 * DIM))[q];
            ax += v * x.x; ay += v * x.y; az += v * x.z; aw += v * x.w;
            v = v1; x = x1;
        }
        ax += v * x.x; ay += v * x.y; az += v * x.z; aw += v * x.w;
    }
    for (int j = start + 64 + g; j < end; j += 4) {
        int2 c = cv[j];
        float vv = __int_as_float(c.y);
        float4 x = ((const float4*)(E + (size_t)c.x * DIM))[q];
        ax += vv * x.x; ay += vv * x.y; az += vv * x.z; aw += vv * x.w;
    }
    ax += __shfl_xor(ax, 16, 64); ay += __shfl_xor(ay, 16, 64);
    az += __shfl_xor(az, 16, 64); aw += __shfl_xor(aw, 16, 64);
    ax += __shfl_xor(ax, 32, 64); ay += __shfl_xor(ay, 32, 64);
    az += __shfl_xor(az, 32, 64); aw += __shfl_xor(aw, 32, 64);
    if (g == 0) {
        float4 p = ((float4*)acc)[q];
        p.x += ax; p.y += ay; p.z += az; p.w += aw;
        ((float4*)acc)[q] = p;
    }
}

// ---- final dot, scale 1/16 --------------------------------------------------
__global__ void dot_out(const float* __restrict__ accU, const float* __restrict__ accI,
                        float* __restrict__ out) {
    int t = blockIdx.x * blockDim.x + threadIdx.x;
    int b = t >> 6, lane = t & 63;
    if (b >= BATCH) return;
    float p = accU[(size_t)b * DIM + lane] * accI[(size_t)b * DIM + lane];
    #pragma unroll
    for (int off = 32; off; off >>= 1) p += __shfl_xor(p, off, 64);
    if (lane == 0) out[b] = p * (1.0f / 16.0f);
}

extern "C" void kernel_launch(void* const* d_in, const int* in_sizes, int n_in,
                              void* d_out, int out_size, void* d_ws, size_t ws_size,
                              hipStream_t stream) {
    const float* emb   = (const float*)d_in[0];
    const int*   Arows = (const int*)d_in[1];
    const int*   Acols = (const int*)d_in[2];
    const float* Avals = (const float*)d_in[3];
    const int*   U     = (const int*)d_in[4];
    const int*   I     = (const int*)d_in[5];
    float* out = (float*)d_out;

    char* ws = (char*)d_ws;
    size_t off = 0;
    auto alloc = [&](size_t bytes) {
        char* p = ws + off;
        off += (bytes + 255) & ~(size_t)255;
        return p;
    };
    float* e0     = (float*)alloc((size_t)N_NODES * DIM * 4);      // 38.4 MB
    float* e1     = (float*)alloc((size_t)N_NODES * DIM * 4);      // 38.4 MB
    int2*  colval = (int2*) alloc(((size_t)NNZ_C + 64) * 8);       // 19.2 MB (row-sorted)
    float* accU   = (float*)alloc((size_t)BATCH * DIM * 4);        // 4.2 MB
    float* accI   = (float*)alloc((size_t)BATCH * DIM * 4);        // 4.2 MB
    int*   rowptr = (int*)  alloc((size_t)(N_NODES + 1) * 4);      // 0.6 MB

    // Build temporaries aliased into e0/e1 (dead before the layers write them)
    int2*           cv_tmp = (int2*)e0;                            // 19.2 MB in e0
    char*           e1c    = (char*)e1;
    unsigned short* rl_tmp = (unsigned short*)e1c;                 // 4.8 MB
    int*            ghist  = (int*)(e1c + (((size_t)NNZ_C * 2 + 255) & ~(size_t)255)); // 172 KB
    int*            btot   = ghist + (size_t)NBUCK * NCHUNK;
    int*            bbase  = btot + NBUCK;                         // NBUCK+1 ints

    // ---- build: chunk histogram -> scans -> bucket scatter -> row sort ----
    k1_hist<<<NCHUNK, 256, 0, stream>>>(Arows, ghist);
    k2a_scan_chunks<<<NBUCK, 512, 0, stream>>>(ghist, btot);
    k2b_scan_buckets<<<1, 256, 0, stream>>>(btot, bbase, rowptr);
    k3_scatter<<<NCHUNK, 256, 0, stream>>>(Arows, Acols, Avals, ghist, bbase,
                                           cv_tmp, rl_tmp);
    k4_sort<<<NBUCK, 256, 0, stream>>>(bbase, cv_tmp, rl_tmp, rowptr, colval);

    int spmm_blocks = (N_NODES * 64 + 255) / 256;
    int bacc_blocks = (BATCH * 64 + 255) / 256;
    int p3_blocks   = (2 * BATCH * 64 + 255) / 256;

    // layer 0
    batch_init<<<bacc_blocks, 256, 0, stream>>>(emb, U, I, accU, accI);
    // layer 1: emb -> e0 (cv_tmp dead from here on)
    spmm_rows<<<spmm_blocks, 256, 0, stream>>>(rowptr, colval, emb, e0);
    batch_acc<<<bacc_blocks, 256, 0, stream>>>(e0, U, I, accU, accI);
    // layer 2: e0 -> e1 (rl_tmp/ghist/btot/bbase dead from here on)
    spmm_rows<<<spmm_blocks, 256, 0, stream>>>(rowptr, colval, e0, e1);
    batch_acc<<<bacc_blocks, 256, 0, stream>>>(e1, U, I, accU, accI);
    // layer 3: only the 2*BATCH rows the output needs
    partial3<<<p3_blocks, 256, 0, stream>>>(rowptr, colval, e1, U, I, accU, accI);
    dot_out<<<bacc_blocks, 256, 0, stream>>>(accU, accI, out);
}

// Round 9
// 283.101 us; speedup vs baseline: 1.2417x; 1.1518x over previous
//
#include <hip/hip_runtime.h>

#define N_USERS 100000
#define N_ITEMS 50000
#define N_NODES 150000
#define DIM 64
#define NNZ_C 2400000
#define BATCH 16384

#define BUCKROWS 512
#define NBUCK ((N_NODES + BUCKROWS - 1) / BUCKROWS)   // 293 buckets of 512 rows
#define CHUNK 8192
#define NCHUNK ((NNZ_C + CHUNK - 1) / CHUNK)          // 293 chunks
#define COLMASK 0x3FFFF                                // 18 bits for col

// ---- k1: per-chunk LDS histogram over 293 buckets -------------------------
__global__ void k1_hist(const int* __restrict__ rows, int* __restrict__ ghist) {
    __shared__ int hist[NBUCK];
    int blk = blockIdx.x, tid = threadIdx.x;
    for (int b = tid; b < NBUCK; b += 256) hist[b] = 0;
    __syncthreads();
    int base = blk * CHUNK;
    int end = min(base + CHUNK, NNZ_C);
    for (int e = base + tid; e < end; e += 256)
        atomicAdd(&hist[rows[e] >> 9], 1);            // LDS atomic
    __syncthreads();
    for (int b = tid; b < NBUCK; b += 256)
        ghist[(size_t)b * NCHUNK + blk] = hist[b];
}

// ---- k2a: per-bucket exclusive scan over NCHUNK (293) entries --------------
__global__ void k2a_scan_chunks(int* __restrict__ ghist, int* __restrict__ btot) {
    __shared__ int s[512];
    int b = blockIdx.x, t = threadIdx.x;
    int v = (t < NCHUNK) ? ghist[(size_t)b * NCHUNK + t] : 0;
    s[t] = v;
    __syncthreads();
    for (int off = 1; off < 512; off <<= 1) {
        int u = (t >= off) ? s[t - off] : 0;
        __syncthreads();
        s[t] += u;
        __syncthreads();
    }
    if (t < NCHUNK) ghist[(size_t)b * NCHUNK + t] = s[t] - v;
    if (t == NCHUNK - 1) btot[b] = s[t];
}

// ---- k2b: exclusive scan of 293 bucket totals ------------------------------
__global__ void k2b_scan_buckets(const int* __restrict__ btot, int* __restrict__ bbase,
                                 int* __restrict__ rowptr) {
    __shared__ int s[512];
    int t = threadIdx.x;
    int v = (t < NBUCK) ? btot[t] : 0;
    s[t] = v;
    __syncthreads();
    for (int off = 1; off < 512; off <<= 1) {
        int u = (t >= off) ? s[t - off] : 0;
        __syncthreads();
        s[t] += u;
        __syncthreads();
    }
    if (t < NBUCK) bbase[t] = s[t] - v;
    if (t == 511) { bbase[NBUCK] = s[511]; rowptr[N_NODES] = NNZ_C; }
}

// ---- k3: scatter edges into bucket order; pack (rl<<18)|col ---------------
__global__ void k3_scatter(const int* __restrict__ rows, const int* __restrict__ cols,
                           const float* __restrict__ vals,
                           const int* __restrict__ ghist, const int* __restrict__ bbase,
                           int2* __restrict__ cv_tmp) {
    __shared__ int cur[NBUCK];
    int blk = blockIdx.x, tid = threadIdx.x;
    for (int b = tid; b < NBUCK; b += 256)
        cur[b] = bbase[b] + ghist[(size_t)b * NCHUNK + blk];
    __syncthreads();
    int base = blk * CHUNK;
    int end = min(base + CHUNK, NNZ_C);
    for (int e = base + tid; e < end; e += 256) {
        int r = rows[e];
        int pos = atomicAdd(&cur[r >> 9], 1);         // LDS atomic
        int2 cv;
        cv.x = ((r & 511) << 18) | cols[e];           // packed rl|col
        cv.y = __float_as_int(vals[e]);
        cv_tmp[pos] = cv;
    }
}

// ---- k4: sort 512 row-locals within each contiguous bucket window ---------
__global__ void k4_sort(const int* __restrict__ bbase,
                        const int2* __restrict__ cv_in,
                        int* __restrict__ rowptr, int2* __restrict__ cv_out) {
    __shared__ int hist[BUCKROWS];      // becomes cursors after scan
    __shared__ int part[256];
    int b = blockIdx.x, tid = threadIdx.x;
    int base = bbase[b];
    int cnt = bbase[b + 1] - base;
    for (int i = tid; i < BUCKROWS; i += 256) hist[i] = 0;
    __syncthreads();
    for (int i = tid; i < cnt; i += 256)
        atomicAdd(&hist[cv_in[base + i].x >> 18], 1);
    __syncthreads();
    int h0 = hist[2 * tid], h1 = hist[2 * tid + 1];
    int sum2 = h0 + h1;
    part[tid] = sum2;
    __syncthreads();
    for (int off = 1; off < 256; off <<= 1) {
        int u = (tid >= off) ? part[tid - off] : 0;
        __syncthreads();
        part[tid] += u;
        __syncthreads();
    }
    int excl = part[tid] - sum2;
    hist[2 * tid]     = excl;
    hist[2 * tid + 1] = excl + h0;
    __syncthreads();
    int rowbase = b * BUCKROWS;
    for (int i = tid; i < BUCKROWS; i += 256) {
        int g = rowbase + i;
        if (g < N_NODES) rowptr[g] = base + hist[i];
    }
    __syncthreads();
    for (int i = tid; i < cnt; i += 256) {
        int2 cv = cv_in[base + i];
        int pos = atomicAdd(&hist[cv.x >> 18], 1);    // LDS cursor
        cv_out[base + pos] = cv;                      // within 64KB window
    }
}

// ---- SpMM: one wave per row; colvals staged via shfl; depth-2 pipeline ----
__global__ void spmm_rows(const int* __restrict__ rowptr, const int2* __restrict__ cv,
                          const float* __restrict__ E, float* __restrict__ Eout) {
    int t = blockIdx.x * blockDim.x + threadIdx.x;
    int row = t >> 6;
    if (row >= N_NODES) return;
    int lane = t & 63;
    int g = lane >> 4, q = lane & 15;
    int ru = __builtin_amdgcn_readfirstlane(row);
    int start = rowptr[ru], end = rowptr[ru + 1];
    int len = end - start;
    int nfull = min(len, 64);
    int2 mycv = cv[start + (lane < nfull ? lane : 0)];
    float ax = 0.f, ay = 0.f, az = 0.f, aw = 0.f;
    int iters = (nfull + 3) >> 2;                     // wave-uniform
    if (iters > 0) {
        int k = g;
        int sc = __shfl(mycv.x, k, 64);
        int sv = __shfl(mycv.y, k, 64);
        bool ok = k < nfull;
        int col = ok ? (sc & COLMASK) : 0;
        float v = ok ? __int_as_float(sv) : 0.f;
        float4 x = ((const float4*)(E + (size_t)col * DIM))[q];
        for (int i = 1; i < iters; ++i) {
            int k1 = g + 4 * i;
            int sc1 = __shfl(mycv.x, k1, 64);
            int sv1 = __shfl(mycv.y, k1, 64);
            bool ok1 = k1 < nfull;
            int col1 = ok1 ? (sc1 & COLMASK) : 0;
            float v1 = ok1 ? __int_as_float(sv1) : 0.f;
            float4 x1 = ((const float4*)(E + (size_t)col1 * DIM))[q];
            ax += v * x.x; ay += v * x.y; az += v * x.z; aw += v * x.w;
            v = v1; x = x1;
        }
        ax += v * x.x; ay += v * x.y; az += v * x.z; aw += v * x.w;
    }
    // rare tail: rows longer than 64 edges
    for (int j = start + 64 + g; j < end; j += 4) {
        int2 c = cv[j];
        float vv = __int_as_float(c.y);
        float4 x = ((const float4*)(E + (size_t)(c.x & COLMASK) * DIM))[q];
        ax += vv * x.x; ay += vv * x.y; az += vv * x.z; aw += vv * x.w;
    }
    ax += __shfl_xor(ax, 16, 64); ay += __shfl_xor(ay, 16, 64);
    az += __shfl_xor(az, 16, 64); aw += __shfl_xor(aw, 16, 64);
    ax += __shfl_xor(ax, 32, 64); ay += __shfl_xor(ay, 32, 64);
    az += __shfl_xor(az, 32, 64); aw += __shfl_xor(aw, 32, 64);
    if (g == 0) {
        float4 o; o.x = ax; o.y = ay; o.z = az; o.w = aw;
        ((float4*)(Eout + (size_t)row * DIM))[q] = o;
    }
}

// ---- b1: acc = emb[row] + e0[row]  (layers 0+1 fused) ----------------------
__global__ void b1_acc(const float* __restrict__ emb, const float* __restrict__ E0,
                       const int* __restrict__ U, const int* __restrict__ I,
                       float* __restrict__ accU, float* __restrict__ accI) {
    int t = blockIdx.x * blockDim.x + threadIdx.x;
    int b = t >> 6, lane = t & 63;
    if (b >= BATCH) return;
    int bu = __builtin_amdgcn_readfirstlane(b);
    int u = U[bu], it = I[bu];
    accU[(size_t)b * DIM + lane] = emb[(size_t)u * DIM + lane] + E0[(size_t)u * DIM + lane];
    accI[(size_t)b * DIM + lane] = emb[(size_t)(N_USERS + it) * DIM + lane]
                                 + E0[(size_t)(N_USERS + it) * DIM + lane];
}

// ---- partial3: acc += e1[row] + A*e1 at batch rows (layers 2+3 fused) ------
__global__ void partial3(const int* __restrict__ rowptr, const int2* __restrict__ cv,
                         const float* __restrict__ E,
                         const int* __restrict__ U, const int* __restrict__ I,
                         float* __restrict__ accU, float* __restrict__ accI) {
    int t = blockIdx.x * blockDim.x + threadIdx.x;
    int s = t >> 6;
    if (s >= 2 * BATCH) return;
    int lane = t & 63;
    int g = lane >> 4, q = lane & 15;
    int su = __builtin_amdgcn_readfirstlane(s);
    int row;
    float* acc;
    if (su < BATCH) {
        row = U[su];
        acc = accU + (size_t)su * DIM;
    } else {
        row = N_USERS + I[su - BATCH];
        acc = accI + (size_t)(su - BATCH) * DIM;
    }
    int start = rowptr[row], end = rowptr[row + 1];
    int len = end - start;
    int nfull = min(len, 64);
    int2 mycv = cv[start + (lane < nfull ? lane : 0)];
    float ax = 0.f, ay = 0.f, az = 0.f, aw = 0.f;
    int iters = (nfull + 3) >> 2;
    if (iters > 0) {
        int k = g;
        int sc = __shfl(mycv.x, k, 64);
        int sv = __shfl(mycv.y, k, 64);
        bool ok = k < nfull;
        int col = ok ? (sc & COLMASK) : 0;
        float v = ok ? __int_as_float(sv) : 0.f;
        float4 x = ((const float4*)(E + (size_t)col * DIM))[q];
        for (int i = 1; i < iters; ++i) {
            int k1 = g + 4 * i;
            int sc1 = __shfl(mycv.x, k1, 64);
            int sv1 = __shfl(mycv.y, k1, 64);
            bool ok1 = k1 < nfull;
            int col1 = ok1 ? (sc1 & COLMASK) : 0;
            float v1 = ok1 ? __int_as_float(sv1) : 0.f;
            float4 x1 = ((const float4*)(E + (size_t)col1 * DIM))[q];
            ax += v * x.x; ay += v * x.y; az += v * x.z; aw += v * x.w;
            v = v1; x = x1;
        }
        ax += v * x.x; ay += v * x.y; az += v * x.z; aw += v * x.w;
    }
    for (int j = start + 64 + g; j < end; j += 4) {
        int2 c = cv[j];
        float vv = __int_as_float(c.y);
        float4 x = ((const float4*)(E + (size_t)(c.x & COLMASK) * DIM))[q];
        ax += vv * x.x; ay += vv * x.y; az += vv * x.z; aw += vv * x.w;
    }
    ax += __shfl_xor(ax, 16, 64); ay += __shfl_xor(ay, 16, 64);
    az += __shfl_xor(az, 16, 64); aw += __shfl_xor(aw, 16, 64);
    ax += __shfl_xor(ax, 32, 64); ay += __shfl_xor(ay, 32, 64);
    az += __shfl_xor(az, 32, 64); aw += __shfl_xor(aw, 32, 64);
    if (g == 0) {
        // add layer-2 self row + layer-3 gathered sum
        float4 self = ((const float4*)(E + (size_t)row * DIM))[q];
        float4 p = ((float4*)acc)[q];
        p.x += ax + self.x; p.y += ay + self.y;
        p.z += az + self.z; p.w += aw + self.w;
        ((float4*)acc)[q] = p;
    }
}

// ---- final dot, scale 1/16 --------------------------------------------------
__global__ void dot_out(const float* __restrict__ accU, const float* __restrict__ accI,
                        float* __restrict__ out) {
    int t = blockIdx.x * blockDim.x + threadIdx.x;
    int b = t >> 6, lane = t & 63;
    if (b >= BATCH) return;
    float p = accU[(size_t)b * DIM + lane] * accI[(size_t)b * DIM + lane];
    #pragma unroll
    for (int off = 32; off; off >>= 1) p += __shfl_xor(p, off, 64);
    if (lane == 0) out[b] = p * (1.0f / 16.0f);
}

extern "C" void kernel_launch(void* const* d_in, const int* in_sizes, int n_in,
                              void* d_out, int out_size, void* d_ws, size_t ws_size,
                              hipStream_t stream) {
    const float* emb   = (const float*)d_in[0];
    const int*   Arows = (const int*)d_in[1];
    const int*   Acols = (const int*)d_in[2];
    const float* Avals = (const float*)d_in[3];
    const int*   U     = (const int*)d_in[4];
    const int*   I     = (const int*)d_in[5];
    float* out = (float*)d_out;

    char* ws = (char*)d_ws;
    size_t off = 0;
    auto alloc = [&](size_t bytes) {
        char* p = ws + off;
        off += (bytes + 255) & ~(size_t)255;
        return p;
    };
    float* e0     = (float*)alloc((size_t)N_NODES * DIM * 4);      // 38.4 MB
    float* e1     = (float*)alloc((size_t)N_NODES * DIM * 4);      // 38.4 MB
    int2*  colval = (int2*) alloc(((size_t)NNZ_C + 64) * 8);       // 19.2 MB (row-sorted)
    float* accU   = (float*)alloc((size_t)BATCH * DIM * 4);        // 4.2 MB
    float* accI   = (float*)alloc((size_t)BATCH * DIM * 4);        // 4.2 MB
    int*   rowptr = (int*)  alloc((size_t)(N_NODES + 1) * 4);      // 0.6 MB

    // Build temporaries aliased into e0/e1 (dead before the layers write them)
    int2* cv_tmp = (int2*)e0;                                      // 19.2 MB in e0
    int*  ghist  = (int*)e1;                                       // 344 KB
    int*  btot   = ghist + (size_t)NBUCK * NCHUNK;
    int*  bbase  = btot + NBUCK;                                   // NBUCK+1 ints

    // ---- build: chunk histogram -> scans -> bucket scatter -> row sort ----
    k1_hist<<<NCHUNK, 256, 0, stream>>>(Arows, ghist);
    k2a_scan_chunks<<<NBUCK, 512, 0, stream>>>(ghist, btot);
    k2b_scan_buckets<<<1, 512, 0, stream>>>(btot, bbase, rowptr);
    k3_scatter<<<NCHUNK, 256, 0, stream>>>(Arows, Acols, Avals, ghist, bbase, cv_tmp);
    k4_sort<<<NBUCK, 256, 0, stream>>>(bbase, cv_tmp, rowptr, colval);

    int spmm_blocks = (N_NODES * 64 + 255) / 256;
    int bacc_blocks = (BATCH * 64 + 255) / 256;
    int p3_blocks   = (2 * BATCH * 64 + 255) / 256;

    // layer 1: emb -> e0 (cv_tmp in e0 dead after k4)
    spmm_rows<<<spmm_blocks, 256, 0, stream>>>(rowptr, colval, emb, e0);
    // layers 0+1 at batch rows
    b1_acc<<<bacc_blocks, 256, 0, stream>>>(emb, e0, U, I, accU, accI);
    // layer 2: e0 -> e1 (ghist/btot/bbase in e1 dead after k4)
    spmm_rows<<<spmm_blocks, 256, 0, stream>>>(rowptr, colval, e0, e1);
    // layers 2+3 at batch rows (self row + gathered layer-3)
    partial3<<<p3_blocks, 256, 0, stream>>>(rowptr, colval, e1, U, I, accU, accI);
    dot_out<<<bacc_blocks, 256, 0, stream>>>(accU, accI, out);
}

// Round 10
// 244.109 us; speedup vs baseline: 1.4401x; 1.1597x over previous
//
#include <hip/hip_runtime.h>

#define N_USERS 100000
#define N_ITEMS 50000
#define N_NODES 150000
#define DIM 64
#define NNZ_C 2400000
#define BATCH 16384

#define BUCKROWS 512
#define NBUCK ((N_NODES + BUCKROWS - 1) / BUCKROWS)   // 293 buckets of 512 rows
#define CHUNK 8192
#define NCHUNK ((NNZ_C + CHUNK - 1) / CHUNK)          // 293 chunks
#define COLMASK 0x3FFFF                                // 18 bits for col

typedef unsigned short ushort_t;

__device__ inline float bf2f(unsigned short h) {
    return __uint_as_float(((unsigned int)h) << 16);
}
__device__ inline unsigned short f2bf(float f) {      // round-to-nearest-even
    unsigned int b = __float_as_uint(f);
    unsigned int r = (b + 0x7FFFu + ((b >> 16) & 1u)) >> 16;
    return (unsigned short)r;
}

// ---- conv: emb f32 -> bf16 table ------------------------------------------
__global__ void conv_bf16(const float* __restrict__ in, ushort_t* __restrict__ outh) {
    int i = blockIdx.x * blockDim.x + threadIdx.x;   // 4 elems/thread
    if (i >= N_NODES * DIM / 4) return;
    float4 v = ((const float4*)in)[i];
    ushort4 h;
    h.x = f2bf(v.x); h.y = f2bf(v.y); h.z = f2bf(v.z); h.w = f2bf(v.w);
    ((ushort4*)outh)[i] = h;
}

// ---- k1: per-chunk LDS histogram over 293 buckets -------------------------
__global__ void k1_hist(const int* __restrict__ rows, int* __restrict__ ghist) {
    __shared__ int hist[NBUCK];
    int blk = blockIdx.x, tid = threadIdx.x;
    for (int b = tid; b < NBUCK; b += 256) hist[b] = 0;
    __syncthreads();
    int base = blk * CHUNK;
    int end = min(base + CHUNK, NNZ_C);
    for (int e = base + tid; e < end; e += 256)
        atomicAdd(&hist[rows[e] >> 9], 1);            // LDS atomic
    __syncthreads();
    for (int b = tid; b < NBUCK; b += 256)
        ghist[(size_t)b * NCHUNK + blk] = hist[b];
}

// ---- k2a: per-bucket exclusive scan over NCHUNK (293) entries --------------
__global__ void k2a_scan_chunks(int* __restrict__ ghist, int* __restrict__ btot) {
    __shared__ int s[512];
    int b = blockIdx.x, t = threadIdx.x;
    int v = (t < NCHUNK) ? ghist[(size_t)b * NCHUNK + t] : 0;
    s[t] = v;
    __syncthreads();
    for (int off = 1; off < 512; off <<= 1) {
        int u = (t >= off) ? s[t - off] : 0;
        __syncthreads();
        s[t] += u;
        __syncthreads();
    }
    if (t < NCHUNK) ghist[(size_t)b * NCHUNK + t] = s[t] - v;
    if (t == NCHUNK - 1) btot[b] = s[t];
}

// ---- k2b: exclusive scan of 293 bucket totals ------------------------------
__global__ void k2b_scan_buckets(const int* __restrict__ btot, int* __restrict__ bbase,
                                 int* __restrict__ rowptr) {
    __shared__ int s[512];
    int t = threadIdx.x;
    int v = (t < NBUCK) ? btot[t] : 0;
    s[t] = v;
    __syncthreads();
    for (int off = 1; off < 512; off <<= 1) {
        int u = (t >= off) ? s[t - off] : 0;
        __syncthreads();
        s[t] += u;
        __syncthreads();
    }
    if (t < NBUCK) bbase[t] = s[t] - v;
    if (t == 511) { bbase[NBUCK] = s[511]; rowptr[N_NODES] = NNZ_C; }
}

// ---- k3: scatter edges into bucket order; pack (rl<<18)|col ---------------
__global__ void k3_scatter(const int* __restrict__ rows, const int* __restrict__ cols,
                           const float* __restrict__ vals,
                           const int* __restrict__ ghist, const int* __restrict__ bbase,
                           int2* __restrict__ cv_tmp) {
    __shared__ int cur[NBUCK];
    int blk = blockIdx.x, tid = threadIdx.x;
    for (int b = tid; b < NBUCK; b += 256)
        cur[b] = bbase[b] + ghist[(size_t)b * NCHUNK + blk];
    __syncthreads();
    int base = blk * CHUNK;
    int end = min(base + CHUNK, NNZ_C);
    for (int e = base + tid; e < end; e += 256) {
        int r = rows[e];
        int pos = atomicAdd(&cur[r >> 9], 1);         // LDS atomic
        int2 cv;
        cv.x = ((r & 511) << 18) | cols[e];           // packed rl|col
        cv.y = __float_as_int(vals[e]);
        cv_tmp[pos] = cv;
    }
}

// ---- k4: sort 512 row-locals within each contiguous bucket window ---------
__global__ void k4_sort(const int* __restrict__ bbase,
                        const int2* __restrict__ cv_in,
                        int* __restrict__ rowptr, int2* __restrict__ cv_out) {
    __shared__ int hist[BUCKROWS];      // becomes cursors after scan
    __shared__ int part[256];
    int b = blockIdx.x, tid = threadIdx.x;
    int base = bbase[b];
    int cnt = bbase[b + 1] - base;
    for (int i = tid; i < BUCKROWS; i += 256) hist[i] = 0;
    __syncthreads();
    for (int i = tid; i < cnt; i += 256)
        atomicAdd(&hist[cv_in[base + i].x >> 18], 1);
    __syncthreads();
    int h0 = hist[2 * tid], h1 = hist[2 * tid + 1];
    int sum2 = h0 + h1;
    part[tid] = sum2;
    __syncthreads();
    for (int off = 1; off < 256; off <<= 1) {
        int u = (tid >= off) ? part[tid - off] : 0;
        __syncthreads();
        part[tid] += u;
        __syncthreads();
    }
    int excl = part[tid] - sum2;
    hist[2 * tid]     = excl;
    hist[2 * tid + 1] = excl + h0;
    __syncthreads();
    int rowbase = b * BUCKROWS;
    for (int i = tid; i < BUCKROWS; i += 256) {
        int g = rowbase + i;
        if (g < N_NODES) rowptr[g] = base + hist[i];
    }
    __syncthreads();
    for (int i = tid; i < cnt; i += 256) {
        int2 cv = cv_in[base + i];
        int pos = atomicAdd(&hist[cv.x >> 18], 1);    // LDS cursor
        cv_out[base + pos] = cv;                      // within 64KB window
    }
}

// ---- SpMM bf16: one wave per row; staged colvals; depth-2 pipeline --------
// Gathers 128B bf16 rows, accumulates f32, writes bf16 row.
__global__ void spmm_rows_h(const int* __restrict__ rowptr, const int2* __restrict__ cv,
                            const ushort_t* __restrict__ Eh, ushort_t* __restrict__ EoutH) {
    int t = blockIdx.x * blockDim.x + threadIdx.x;
    int row = t >> 6;
    if (row >= N_NODES) return;
    int lane = t & 63;
    int g = lane >> 4, q = lane & 15;
    int ru = __builtin_amdgcn_readfirstlane(row);
    int start = rowptr[ru], end = rowptr[ru + 1];
    int len = end - start;
    int nfull = min(len, 64);
    int2 mycv = cv[start + (lane < nfull ? lane : 0)];
    float ax = 0.f, ay = 0.f, az = 0.f, aw = 0.f;
    int iters = (nfull + 3) >> 2;                     // wave-uniform
    if (iters > 0) {
        int k = g;
        int sc = __shfl(mycv.x, k, 64);
        int sv = __shfl(mycv.y, k, 64);
        bool ok = k < nfull;
        int col = ok ? (sc & COLMASK) : 0;
        float v = ok ? __int_as_float(sv) : 0.f;
        ushort4 raw = ((const ushort4*)(Eh + (size_t)col * DIM))[q];
        for (int i = 1; i < iters; ++i) {
            int k1 = g + 4 * i;
            int sc1 = __shfl(mycv.x, k1, 64);
            int sv1 = __shfl(mycv.y, k1, 64);
            bool ok1 = k1 < nfull;
            int col1 = ok1 ? (sc1 & COLMASK) : 0;
            float v1 = ok1 ? __int_as_float(sv1) : 0.f;
            ushort4 raw1 = ((const ushort4*)(Eh + (size_t)col1 * DIM))[q];
            ax += v * bf2f(raw.x); ay += v * bf2f(raw.y);
            az += v * bf2f(raw.z); aw += v * bf2f(raw.w);
            v = v1; raw = raw1;
        }
        ax += v * bf2f(raw.x); ay += v * bf2f(raw.y);
        az += v * bf2f(raw.z); aw += v * bf2f(raw.w);
    }
    // rare tail: rows longer than 64 edges
    for (int j = start + 64 + g; j < end; j += 4) {
        int2 c = cv[j];
        float vv = __int_as_float(c.y);
        ushort4 raw = ((const ushort4*)(Eh + (size_t)(c.x & COLMASK) * DIM))[q];
        ax += vv * bf2f(raw.x); ay += vv * bf2f(raw.y);
        az += vv * bf2f(raw.z); aw += vv * bf2f(raw.w);
    }
    ax += __shfl_xor(ax, 16, 64); ay += __shfl_xor(ay, 16, 64);
    az += __shfl_xor(az, 16, 64); aw += __shfl_xor(aw, 16, 64);
    ax += __shfl_xor(ax, 32, 64); ay += __shfl_xor(ay, 32, 64);
    az += __shfl_xor(az, 32, 64); aw += __shfl_xor(aw, 32, 64);
    if (g == 0) {
        ushort4 o;
        o.x = f2bf(ax); o.y = f2bf(ay); o.z = f2bf(az); o.w = f2bf(aw);
        ((ushort4*)(EoutH + (size_t)row * DIM))[q] = o;
    }
}

// ---- b1: acc = emb_f32[row] + e0_h[row]  (layers 0+1 fused) ----------------
__global__ void b1_acc(const float* __restrict__ emb, const ushort_t* __restrict__ E0h,
                       const int* __restrict__ U, const int* __restrict__ I,
                       float* __restrict__ accU, float* __restrict__ accI) {
    int t = blockIdx.x * blockDim.x + threadIdx.x;
    int b = t >> 6, lane = t & 63;
    if (b >= BATCH) return;
    int bu = __builtin_amdgcn_readfirstlane(b);
    int u = U[bu], it = I[bu];
    accU[(size_t)b * DIM + lane] = emb[(size_t)u * DIM + lane]
                                 + bf2f(E0h[(size_t)u * DIM + lane]);
    accI[(size_t)b * DIM + lane] = emb[(size_t)(N_USERS + it) * DIM + lane]
                                 + bf2f(E0h[(size_t)(N_USERS + it) * DIM + lane]);
}

// ---- partial3: acc += e1[row] + (A*e1)[row] at batch rows (layers 2+3) -----
__global__ void partial3(const int* __restrict__ rowptr, const int2* __restrict__ cv,
                         const ushort_t* __restrict__ Eh,
                         const int* __restrict__ U, const int* __restrict__ I,
                         float* __restrict__ accU, float* __restrict__ accI) {
    int t = blockIdx.x * blockDim.x + threadIdx.x;
    int s = t >> 6;
    if (s >= 2 * BATCH) return;
    int lane = t & 63;
    int g = lane >> 4, q = lane & 15;
    int su = __builtin_amdgcn_readfirstlane(s);
    int row;
    float* acc;
    if (su < BATCH) {
        row = U[su];
        acc = accU + (size_t)su * DIM;
    } else {
        row = N_USERS + I[su - BATCH];
        acc = accI + (size_t)(su - BATCH) * DIM;
    }
    int start = rowptr[row], end = rowptr[row + 1];
    int len = end - start;
    int nfull = min(len, 64);
    int2 mycv = cv[start + (lane < nfull ? lane : 0)];
    float ax = 0.f, ay = 0.f, az = 0.f, aw = 0.f;
    int iters = (nfull + 3) >> 2;
    if (iters > 0) {
        int k = g;
        int sc = __shfl(mycv.x, k, 64);
        int sv = __shfl(mycv.y, k, 64);
        bool ok = k < nfull;
        int col = ok ? (sc & COLMASK) : 0;
        float v = ok ? __int_as_float(sv) : 0.f;
        ushort4 raw = ((const ushort4*)(Eh + (size_t)col * DIM))[q];
        for (int i = 1; i < iters; ++i) {
            int k1 = g + 4 * i;
            int sc1 = __shfl(mycv.x, k1, 64);
            int sv1 = __shfl(mycv.y, k1, 64);
            bool ok1 = k1 < nfull;
            int col1 = ok1 ? (sc1 & COLMASK) : 0;
            float v1 = ok1 ? __int_as_float(sv1) : 0.f;
            ushort4 raw1 = ((const ushort4*)(Eh + (size_t)col1 * DIM))[q];
            ax += v * bf2f(raw.x); ay += v * bf2f(raw.y);
            az += v * bf2f(raw.z); aw += v * bf2f(raw.w);
            v = v1; raw = raw1;
        }
        ax += v * bf2f(raw.x); ay += v * bf2f(raw.y);
        az += v * bf2f(raw.z); aw += v * bf2f(raw.w);
    }
    for (int j = start + 64 + g; j < end; j += 4) {
        int2 c = cv[j];
        float vv = __int_as_float(c.y);
        ushort4 raw = ((const ushort4*)(Eh + (size_t)(c.x & COLMASK) * DIM))[q];
        ax += vv * bf2f(raw.x); ay += vv * bf2f(raw.y);
        az += vv * bf2f(raw.z); aw += vv * bf2f(raw.w);
    }
    ax += __shfl_xor(ax, 16, 64); ay += __shfl_xor(ay, 16, 64);
    az += __shfl_xor(az, 16, 64); aw += __shfl_xor(aw, 16, 64);
    ax += __shfl_xor(ax, 32, 64); ay += __shfl_xor(ay, 32, 64);
    az += __shfl_xor(az, 32, 64); aw += __shfl_xor(aw, 32, 64);
    if (g == 0) {
        ushort4 sr = ((const ushort4*)(Eh + (size_t)row * DIM))[q];  // layer-2 self row
        float4 p = ((float4*)acc)[q];
        p.x += ax + bf2f(sr.x); p.y += ay + bf2f(sr.y);
        p.z += az + bf2f(sr.z); p.w += aw + bf2f(sr.w);
        ((float4*)acc)[q] = p;
    }
}

// ---- final dot, scale 1/16 --------------------------------------------------
__global__ void dot_out(const float* __restrict__ accU, const float* __restrict__ accI,
                        float* __restrict__ out) {
    int t = blockIdx.x * blockDim.x + threadIdx.x;
    int b = t >> 6, lane = t & 63;
    if (b >= BATCH) return;
    float p = accU[(size_t)b * DIM + lane] * accI[(size_t)b * DIM + lane];
    #pragma unroll
    for (int off = 32; off; off >>= 1) p += __shfl_xor(p, off, 64);
    if (lane == 0) out[b] = p * (1.0f / 16.0f);
}

extern "C" void kernel_launch(void* const* d_in, const int* in_sizes, int n_in,
                              void* d_out, int out_size, void* d_ws, size_t ws_size,
                              hipStream_t stream) {
    const float* emb   = (const float*)d_in[0];
    const int*   Arows = (const int*)d_in[1];
    const int*   Acols = (const int*)d_in[2];
    const float* Avals = (const float*)d_in[3];
    const int*   U     = (const int*)d_in[4];
    const int*   I     = (const int*)d_in[5];
    float* out = (float*)d_out;

    char* ws = (char*)d_ws;
    size_t off = 0;
    auto alloc = [&](size_t bytes) {
        char* p = ws + off;
        off += (bytes + 255) & ~(size_t)255;
        return p;
    };
    ushort_t* emb_h  = (ushort_t*)alloc((size_t)N_NODES * DIM * 2);   // 19.2 MB
    ushort_t* e0_h   = (ushort_t*)alloc((size_t)N_NODES * DIM * 2);   // 19.2 MB
    ushort_t* e1_h   = (ushort_t*)alloc((size_t)N_NODES * DIM * 2);   // 19.2 MB
    int2*     colval = (int2*)    alloc(((size_t)NNZ_C + 64) * 8);    // 19.2 MB (row-sorted)
    int2*     cv_tmp = (int2*)    alloc(((size_t)NNZ_C + 64) * 8);    // 19.2 MB (bucket-grouped)
    float*    accU   = (float*)   alloc((size_t)BATCH * DIM * 4);     // 4.2 MB
    float*    accI   = (float*)   alloc((size_t)BATCH * DIM * 4);     // 4.2 MB
    int*      rowptr = (int*)     alloc((size_t)(N_NODES + 1) * 4);   // 0.6 MB
    int*      ghist  = (int*)     alloc((size_t)NBUCK * NCHUNK * 4);  // 344 KB
    int*      btot   = (int*)     alloc((size_t)NBUCK * 4);
    int*      bbase  = (int*)     alloc((size_t)(NBUCK + 1) * 4);
    // total ~106 MB

    // ---- emb -> bf16 table (independent of edge build) ----
    conv_bf16<<<(N_NODES * DIM / 4 + 255) / 256, 256, 0, stream>>>(emb, emb_h);

    // ---- build: chunk histogram -> scans -> bucket scatter -> row sort ----
    k1_hist<<<NCHUNK, 256, 0, stream>>>(Arows, ghist);
    k2a_scan_chunks<<<NBUCK, 512, 0, stream>>>(ghist, btot);
    k2b_scan_buckets<<<1, 512, 0, stream>>>(btot, bbase, rowptr);
    k3_scatter<<<NCHUNK, 256, 0, stream>>>(Arows, Acols, Avals, ghist, bbase, cv_tmp);
    k4_sort<<<NBUCK, 256, 0, stream>>>(bbase, cv_tmp, rowptr, colval);

    int spmm_blocks = (N_NODES * 64 + 255) / 256;
    int bacc_blocks = (BATCH * 64 + 255) / 256;
    int p3_blocks   = (2 * BATCH * 64 + 255) / 256;

    // layer 1: emb_h -> e0_h
    spmm_rows_h<<<spmm_blocks, 256, 0, stream>>>(rowptr, colval, emb_h, e0_h);
    // layers 0+1 at batch rows (emb in f32 for accuracy, e0 bf16)
    b1_acc<<<bacc_blocks, 256, 0, stream>>>(emb, e0_h, U, I, accU, accI);
    // layer 2: e0_h -> e1_h
    spmm_rows_h<<<spmm_blocks, 256, 0, stream>>>(rowptr, colval, e0_h, e1_h);
    // layers 2+3 at batch rows (self row + gathered layer-3)
    partial3<<<p3_blocks, 256, 0, stream>>>(rowptr, colval, e1_h, U, I, accU, accI);
    dot_out<<<bacc_blocks, 256, 0, stream>>>(accU, accI, out);
}

// Round 11
// 221.271 us; speedup vs baseline: 1.5887x; 1.1032x over previous
//
#include <hip/hip_runtime.h>

#define N_USERS 100000
#define N_ITEMS 50000
#define N_NODES 150000
#define DIM 64
#define NNZ_C 2400000
#define BATCH 16384

#define BUCKROWS 512
#define NBUCK ((N_NODES + BUCKROWS - 1) / BUCKROWS)   // 293 buckets of 512 rows
#define CHUNK 8192
#define NCHUNK ((NNZ_C + CHUNK - 1) / CHUNK)          // 293 chunks
#define COLMASK 0x3FFFF                                // 18 bits for col
#define CONVBLK ((N_NODES * DIM / 4 + 255) / 256)      // 9375

typedef unsigned short ushort_t;

__device__ inline unsigned short f2bf(float f) {      // round-to-nearest-even
    unsigned int b = __float_as_uint(f);
    unsigned int r = (b + 0x7FFFu + ((b >> 16) & 1u)) >> 16;
    return (unsigned short)r;
}
__device__ inline float bflo(unsigned int u) { return __uint_as_float(u << 16); }
__device__ inline float bfhi(unsigned int u) { return __uint_as_float(u & 0xFFFF0000u); }

// ---- fused: k1 chunk-histogram (blocks 0..NCHUNK) + emb->bf16 conv --------
__global__ void k1_conv(const int* __restrict__ rows, int* __restrict__ ghist,
                        const float* __restrict__ emb, ushort_t* __restrict__ embh) {
    __shared__ int hist[NBUCK];
    int blk = blockIdx.x, tid = threadIdx.x;
    if (blk < NCHUNK) {
        for (int b = tid; b < NBUCK; b += 256) hist[b] = 0;
        __syncthreads();
        int base = blk * CHUNK;
        int end = min(base + CHUNK, NNZ_C);
        for (int e = base + tid; e < end; e += 256)
            atomicAdd(&hist[rows[e] >> 9], 1);        // LDS atomic
        __syncthreads();
        for (int b = tid; b < NBUCK; b += 256)
            ghist[(size_t)b * NCHUNK + blk] = hist[b];
    } else {
        int i = (blk - NCHUNK) * 256 + tid;           // 4 elems/thread
        if (i < N_NODES * DIM / 4) {
            float4 v = ((const float4*)emb)[i];
            ushort4 h;
            h.x = f2bf(v.x); h.y = f2bf(v.y); h.z = f2bf(v.z); h.w = f2bf(v.w);
            ((ushort4*)embh)[i] = h;
        }
    }
}

// ---- k2a: per-bucket exclusive scan over NCHUNK (293) entries --------------
__global__ void k2a_scan_chunks(int* __restrict__ ghist, int* __restrict__ btot) {
    __shared__ int s[512];
    int b = blockIdx.x, t = threadIdx.x;
    int v = (t < NCHUNK) ? ghist[(size_t)b * NCHUNK + t] : 0;
    s[t] = v;
    __syncthreads();
    for (int off = 1; off < 512; off <<= 1) {
        int u = (t >= off) ? s[t - off] : 0;
        __syncthreads();
        s[t] += u;
        __syncthreads();
    }
    if (t < NCHUNK) ghist[(size_t)b * NCHUNK + t] = s[t] - v;
    if (t == NCHUNK - 1) btot[b] = s[t];
}

// ---- k2b: exclusive scan of 293 bucket totals ------------------------------
__global__ void k2b_scan_buckets(const int* __restrict__ btot, int* __restrict__ bbase,
                                 int* __restrict__ rowptr) {
    __shared__ int s[512];
    int t = threadIdx.x;
    int v = (t < NBUCK) ? btot[t] : 0;
    s[t] = v;
    __syncthreads();
    for (int off = 1; off < 512; off <<= 1) {
        int u = (t >= off) ? s[t - off] : 0;
        __syncthreads();
        s[t] += u;
        __syncthreads();
    }
    if (t < NBUCK) bbase[t] = s[t] - v;
    if (t == 511) { bbase[NBUCK] = s[511]; rowptr[N_NODES] = NNZ_C; }
}

// ---- k3: scatter edges into bucket order; pack (rl<<18)|col ---------------
__global__ void k3_scatter(const int* __restrict__ rows, const int* __restrict__ cols,
                           const float* __restrict__ vals,
                           const int* __restrict__ ghist, const int* __restrict__ bbase,
                           int2* __restrict__ cv_tmp) {
    __shared__ int cur[NBUCK];
    int blk = blockIdx.x, tid = threadIdx.x;
    for (int b = tid; b < NBUCK; b += 256)
        cur[b] = bbase[b] + ghist[(size_t)b * NCHUNK + blk];
    __syncthreads();
    int base = blk * CHUNK;
    int end = min(base + CHUNK, NNZ_C);
    for (int e = base + tid; e < end; e += 256) {
        int r = rows[e];
        int pos = atomicAdd(&cur[r >> 9], 1);         // LDS atomic
        int2 cv;
        cv.x = ((r & 511) << 18) | cols[e];           // packed rl|col
        cv.y = __float_as_int(vals[e]);
        cv_tmp[pos] = cv;
    }
}

// ---- k4: sort 512 row-locals within each contiguous bucket window ---------
__global__ void k4_sort(const int* __restrict__ bbase,
                        const int2* __restrict__ cv_in,
                        int* __restrict__ rowptr, int2* __restrict__ cv_out) {
    __shared__ int hist[BUCKROWS];      // becomes cursors after scan
    __shared__ int part[256];
    int b = blockIdx.x, tid = threadIdx.x;
    int base = bbase[b];
    int cnt = bbase[b + 1] - base;
    for (int i = tid; i < BUCKROWS; i += 256) hist[i] = 0;
    __syncthreads();
    for (int i = tid; i < cnt; i += 256)
        atomicAdd(&hist[cv_in[base + i].x >> 18], 1);
    __syncthreads();
    int h0 = hist[2 * tid], h1 = hist[2 * tid + 1];
    int sum2 = h0 + h1;
    part[tid] = sum2;
    __syncthreads();
    for (int off = 1; off < 256; off <<= 1) {
        int u = (tid >= off) ? part[tid - off] : 0;
        __syncthreads();
        part[tid] += u;
        __syncthreads();
    }
    int excl = part[tid] - sum2;
    hist[2 * tid]     = excl;
    hist[2 * tid + 1] = excl + h0;
    __syncthreads();
    int rowbase = b * BUCKROWS;
    for (int i = tid; i < BUCKROWS; i += 256) {
        int g = rowbase + i;
        if (g < N_NODES) rowptr[g] = base + hist[i];
    }
    __syncthreads();
    for (int i = tid; i < cnt; i += 256) {
        int2 cv = cv_in[base + i];
        int pos = atomicAdd(&hist[cv.x >> 18], 1);    // LDS cursor
        cv_out[base + pos] = cv;                      // within 64KB window
    }
}

#define STAGE8(i, VV, RR) { int kk = g + 8 * (i);                            \
    VV = __shfl(my_v, kk, 64);                                               \
    int cc = __shfl(my_c, kk, 64);                                           \
    RR = ((const uint4*)(Eh + (size_t)cc * DIM))[q]; }

#define CONS8(VV, RR) {                                                      \
    a0 += VV * bflo(RR.x); a1 += VV * bfhi(RR.x);                            \
    a2 += VV * bflo(RR.y); a3 += VV * bfhi(RR.y);                            \
    a4 += VV * bflo(RR.z); a5 += VV * bfhi(RR.z);                            \
    a6 += VV * bflo(RR.w); a7 += VV * bfhi(RR.w); }

#define GATHER_BODY                                                          \
    int start = rowptr[ru], end = rowptr[ru + 1];                            \
    int len = end - start;                                                   \
    int nfull = min(len, 64);                                                \
    int2 mycv = cv[start + lane];                                            \
    float my_v = (lane < nfull) ? __int_as_float(mycv.y) : 0.f;              \
    int   my_c = mycv.x & COLMASK;                                           \
    float a0=0,a1=0,a2=0,a3=0,a4=0,a5=0,a6=0,a7=0;                           \
    int iters = (nfull + 7) >> 3;                                            \
    if (iters > 0) {                                                         \
        float va, vb, vc; uint4 ra, rb, rc;                                  \
        STAGE8(0, va, ra);                                                   \
        if (iters > 1) STAGE8(1, vb, rb);                                    \
        for (int i = 2; i < iters; ++i) {                                    \
            STAGE8(i, vc, rc);                                               \
            CONS8(va, ra);                                                   \
            va = vb; ra = rb; vb = vc; rb = rc;                              \
        }                                                                    \
        CONS8(va, ra);                                                       \
        if (iters > 1) CONS8(vb, rb);                                        \
    }                                                                        \
    for (int j = start + 64 + g; j < end; j += 8) {                          \
        int2 c = cv[j];                                                      \
        float vv = __int_as_float(c.y);                                      \
        uint4 rr = ((const uint4*)(Eh + (size_t)(c.x & COLMASK) * DIM))[q];  \
        CONS8(vv, rr);                                                       \
    }                                                                        \
    _Pragma("unroll")                                                        \
    for (int off = 8; off <= 32; off <<= 1) {                                \
        a0 += __shfl_xor(a0, off, 64); a1 += __shfl_xor(a1, off, 64);        \
        a2 += __shfl_xor(a2, off, 64); a3 += __shfl_xor(a3, off, 64);        \
        a4 += __shfl_xor(a4, off, 64); a5 += __shfl_xor(a5, off, 64);        \
        a6 += __shfl_xor(a6, off, 64); a7 += __shfl_xor(a7, off, 64);        \
    }

// ---- SpMM bf16: one wave per row; 8 lanes/edge x 16B; depth-3 pipeline ----
__global__ void spmm_rows_h(const int* __restrict__ rowptr, const int2* __restrict__ cv,
                            const ushort_t* __restrict__ Eh, ushort_t* __restrict__ EoutH) {
    int t = blockIdx.x * blockDim.x + threadIdx.x;
    int row = t >> 6;
    if (row >= N_NODES) return;
    int lane = t & 63;
    int g = lane >> 3, q = lane & 7;
    int ru = __builtin_amdgcn_readfirstlane(row);
    GATHER_BODY
    if (g == 0) {
        uint4 o;
        o.x = (unsigned)f2bf(a0) | ((unsigned)f2bf(a1) << 16);
        o.y = (unsigned)f2bf(a2) | ((unsigned)f2bf(a3) << 16);
        o.z = (unsigned)f2bf(a4) | ((unsigned)f2bf(a5) << 16);
        o.w = (unsigned)f2bf(a6) | ((unsigned)f2bf(a7) << 16);
        ((uint4*)(EoutH + (size_t)row * DIM))[q] = o;
    }
}

// ---- partial3f: acc = emb + e0 + e1 + (A*e1) at batch rows (b1 folded) ----
__global__ void partial3f(const int* __restrict__ rowptr, const int2* __restrict__ cv,
                          const ushort_t* __restrict__ Eh,      // e1
                          const ushort_t* __restrict__ E0h,     // e0
                          const float* __restrict__ emb,
                          const int* __restrict__ U, const int* __restrict__ I,
                          float* __restrict__ accU, float* __restrict__ accI) {
    int t = blockIdx.x * blockDim.x + threadIdx.x;
    int s = t >> 6;
    if (s >= 2 * BATCH) return;
    int lane = t & 63;
    int g = lane >> 3, q = lane & 7;
    int su = __builtin_amdgcn_readfirstlane(s);
    int row;
    float* acc;
    if (su < BATCH) {
        row = U[su];
        acc = accU + (size_t)su * DIM;
    } else {
        row = N_USERS + I[su - BATCH];
        acc = accI + (size_t)(su - BATCH) * DIM;
    }
    int ru = row;
    GATHER_BODY
    if (g == 0) {
        const float4* ef = (const float4*)(emb + (size_t)row * DIM);
        float4 ea = ef[2 * q], eb = ef[2 * q + 1];
        uint4 s0 = ((const uint4*)(E0h + (size_t)row * DIM))[q];
        uint4 s1 = ((const uint4*)(Eh  + (size_t)row * DIM))[q];
        float4 pa, pb;
        pa.x = ea.x + bflo(s0.x) + bflo(s1.x) + a0;
        pa.y = ea.y + bfhi(s0.x) + bfhi(s1.x) + a1;
        pa.z = ea.z + bflo(s0.y) + bflo(s1.y) + a2;
        pa.w = ea.w + bfhi(s0.y) + bfhi(s1.y) + a3;
        pb.x = eb.x + bflo(s0.z) + bflo(s1.z) + a4;
        pb.y = eb.y + bfhi(s0.z) + bfhi(s1.z) + a5;
        pb.z = eb.z + bflo(s0.w) + bflo(s1.w) + a6;
        pb.w = eb.w + bfhi(s0.w) + bfhi(s1.w) + a7;
        ((float4*)acc)[2 * q]     = pa;
        ((float4*)acc)[2 * q + 1] = pb;
    }
}

// ---- final dot, scale 1/16 --------------------------------------------------
__global__ void dot_out(const float* __restrict__ accU, const float* __restrict__ accI,
                        float* __restrict__ out) {
    int t = blockIdx.x * blockDim.x + threadIdx.x;
    int b = t >> 6, lane = t & 63;
    if (b >= BATCH) return;
    float p = accU[(size_t)b * DIM + lane] * accI[(size_t)b * DIM + lane];
    #pragma unroll
    for (int off = 32; off; off >>= 1) p += __shfl_xor(p, off, 64);
    if (lane == 0) out[b] = p * (1.0f / 16.0f);
}

extern "C" void kernel_launch(void* const* d_in, const int* in_sizes, int n_in,
                              void* d_out, int out_size, void* d_ws, size_t ws_size,
                              hipStream_t stream) {
    const float* emb   = (const float*)d_in[0];
    const int*   Arows = (const int*)d_in[1];
    const int*   Acols = (const int*)d_in[2];
    const float* Avals = (const float*)d_in[3];
    const int*   U     = (const int*)d_in[4];
    const int*   I     = (const int*)d_in[5];
    float* out = (float*)d_out;

    char* ws = (char*)d_ws;
    size_t off = 0;
    auto alloc = [&](size_t bytes) {
        char* p = ws + off;
        off += (bytes + 255) & ~(size_t)255;
        return p;
    };
    ushort_t* emb_h  = (ushort_t*)alloc((size_t)N_NODES * DIM * 2);   // 19.2 MB
    ushort_t* e0_h   = (ushort_t*)alloc((size_t)N_NODES * DIM * 2);   // 19.2 MB
    ushort_t* e1_h   = (ushort_t*)alloc((size_t)N_NODES * DIM * 2);   // 19.2 MB
    int2*     colval = (int2*)    alloc(((size_t)NNZ_C + 64) * 8);    // 19.2 MB (row-sorted)
    int2*     cv_tmp = (int2*)    alloc(((size_t)NNZ_C + 64) * 8);    // 19.2 MB (bucket-grouped)
    float*    accU   = (float*)   alloc((size_t)BATCH * DIM * 4);     // 4.2 MB
    float*    accI   = (float*)   alloc((size_t)BATCH * DIM * 4);     // 4.2 MB
    int*      rowptr = (int*)     alloc((size_t)(N_NODES + 1) * 4);   // 0.6 MB
    int*      ghist  = (int*)     alloc((size_t)NBUCK * NCHUNK * 4);  // 344 KB
    int*      btot   = (int*)     alloc((size_t)NBUCK * 4);
    int*      bbase  = (int*)     alloc((size_t)(NBUCK + 1) * 4);

    // ---- build (+ emb->bf16 conv fused with k1) ----
    k1_conv<<<NCHUNK + CONVBLK, 256, 0, stream>>>(Arows, ghist, emb, emb_h);
    k2a_scan_chunks<<<NBUCK, 512, 0, stream>>>(ghist, btot);
    k2b_scan_buckets<<<1, 512, 0, stream>>>(btot, bbase, rowptr);
    k3_scatter<<<NCHUNK, 256, 0, stream>>>(Arows, Acols, Avals, ghist, bbase, cv_tmp);
    k4_sort<<<NBUCK, 256, 0, stream>>>(bbase, cv_tmp, rowptr, colval);

    int spmm_blocks = (N_NODES * 64 + 255) / 256;
    int bacc_blocks = (BATCH * 64 + 255) / 256;
    int p3_blocks   = (2 * BATCH * 64 + 255) / 256;

    // layer 1: emb_h -> e0_h
    spmm_rows_h<<<spmm_blocks, 256, 0, stream>>>(rowptr, colval, emb_h, e0_h);
    // layer 2: e0_h -> e1_h
    spmm_rows_h<<<spmm_blocks, 256, 0, stream>>>(rowptr, colval, e0_h, e1_h);
    // layers 0..3 at batch rows: acc = emb + e0 + e1 + A*e1
    partial3f<<<p3_blocks, 256, 0, stream>>>(rowptr, colval, e1_h, e0_h, emb,
                                             U, I, accU, accI);
    dot_out<<<bacc_blocks, 256, 0, stream>>>(accU, accI, out);
}

// Round 12
// 204.136 us; speedup vs baseline: 1.7221x; 1.0839x over previous
//
#include <hip/hip_runtime.h>

#define N_USERS 100000
#define N_ITEMS 50000
#define N_NODES 150000
#define DIM 64
#define NNZ_C 2400000
#define BATCH 16384

#define BUCKROWS 512
#define NBUCK ((N_NODES + BUCKROWS - 1) / BUCKROWS)   // 293 buckets of 512 rows
#define CHUNK 8192
#define NCHUNK ((NNZ_C + CHUNK - 1) / CHUNK)          // 293 chunks
#define COLMASK 0x3FFFF                                // 18 bits for col
#define CONVBLK ((N_NODES * DIM / 4 + 255) / 256)      // 9375

typedef unsigned short ushort_t;
typedef float f32x4 __attribute__((ext_vector_type(4)));

__device__ inline unsigned short f2bf(float f) {      // round-to-nearest-even
    unsigned int b = __float_as_uint(f);
    unsigned int r = (b + 0x7FFFu + ((b >> 16) & 1u)) >> 16;
    return (unsigned short)r;
}
__device__ inline float bflo(unsigned int u) { return __uint_as_float(u << 16); }
__device__ inline float bfhi(unsigned int u) { return __uint_as_float(u & 0xFFFF0000u); }

// ---- fused: k1 chunk-histogram (blocks 0..NCHUNK) + emb->bf16 conv --------
__global__ void k1_conv(const int* __restrict__ rows, int* __restrict__ ghist,
                        const float* __restrict__ emb, ushort_t* __restrict__ embh) {
    __shared__ int hist[NBUCK];
    int blk = blockIdx.x, tid = threadIdx.x;
    if (blk < NCHUNK) {
        for (int b = tid; b < NBUCK; b += 256) hist[b] = 0;
        __syncthreads();
        int base = blk * CHUNK;
        int end = min(base + CHUNK, NNZ_C);
        for (int e = base + tid; e < end; e += 256)
            atomicAdd(&hist[rows[e] >> 9], 1);        // LDS atomic
        __syncthreads();
        for (int b = tid; b < NBUCK; b += 256)
            ghist[(size_t)b * NCHUNK + blk] = hist[b];
    } else {
        int i = (blk - NCHUNK) * 256 + tid;           // 4 elems/thread
        if (i < N_NODES * DIM / 4) {
            float4 v = ((const float4*)emb)[i];
            ushort4 h;
            h.x = f2bf(v.x); h.y = f2bf(v.y); h.z = f2bf(v.z); h.w = f2bf(v.w);
            ((ushort4*)embh)[i] = h;
        }
    }
}

// ---- k2a: per-bucket exclusive scan over NCHUNK (293) entries --------------
__global__ void k2a_scan_chunks(int* __restrict__ ghist, int* __restrict__ btot) {
    __shared__ int s[512];
    int b = blockIdx.x, t = threadIdx.x;
    int v = (t < NCHUNK) ? ghist[(size_t)b * NCHUNK + t] : 0;
    s[t] = v;
    __syncthreads();
    for (int off = 1; off < 512; off <<= 1) {
        int u = (t >= off) ? s[t - off] : 0;
        __syncthreads();
        s[t] += u;
        __syncthreads();
    }
    if (t < NCHUNK) ghist[(size_t)b * NCHUNK + t] = s[t] - v;
    if (t == NCHUNK - 1) btot[b] = s[t];
}

// ---- k2b: exclusive scan of 293 bucket totals ------------------------------
__global__ void k2b_scan_buckets(const int* __restrict__ btot, int* __restrict__ bbase,
                                 int* __restrict__ rowptr) {
    __shared__ int s[512];
    int t = threadIdx.x;
    int v = (t < NBUCK) ? btot[t] : 0;
    s[t] = v;
    __syncthreads();
    for (int off = 1; off < 512; off <<= 1) {
        int u = (t >= off) ? s[t - off] : 0;
        __syncthreads();
        s[t] += u;
        __syncthreads();
    }
    if (t < NBUCK) bbase[t] = s[t] - v;
    if (t == 511) { bbase[NBUCK] = s[511]; rowptr[N_NODES] = NNZ_C; }
}

// ---- k3: scatter edges into bucket order; pack (rl<<18)|col ---------------
__global__ void k3_scatter(const int* __restrict__ rows, const int* __restrict__ cols,
                           const float* __restrict__ vals,
                           const int* __restrict__ ghist, const int* __restrict__ bbase,
                           int2* __restrict__ cv_tmp) {
    __shared__ int cur[NBUCK];
    int blk = blockIdx.x, tid = threadIdx.x;
    for (int b = tid; b < NBUCK; b += 256)
        cur[b] = bbase[b] + ghist[(size_t)b * NCHUNK + blk];
    __syncthreads();
    int base = blk * CHUNK;
    int end = min(base + CHUNK, NNZ_C);
    for (int e = base + tid; e < end; e += 256) {
        int r = rows[e];
        int pos = atomicAdd(&cur[r >> 9], 1);         // LDS atomic
        int2 cv;
        cv.x = ((r & 511) << 18) | cols[e];           // packed rl|col
        cv.y = __float_as_int(vals[e]);
        cv_tmp[pos] = cv;
    }
}

// ---- k4: sort 512 row-locals within each contiguous bucket window ---------
__global__ void k4_sort(const int* __restrict__ bbase,
                        const int2* __restrict__ cv_in,
                        int* __restrict__ rowptr, int2* __restrict__ cv_out) {
    __shared__ int hist[BUCKROWS];      // becomes cursors after scan
    __shared__ int part[256];
    int b = blockIdx.x, tid = threadIdx.x;
    int base = bbase[b];
    int cnt = bbase[b + 1] - base;
    for (int i = tid; i < BUCKROWS; i += 256) hist[i] = 0;
    __syncthreads();
    for (int i = tid; i < cnt; i += 256)
        atomicAdd(&hist[cv_in[base + i].x >> 18], 1);
    __syncthreads();
    int h0 = hist[2 * tid], h1 = hist[2 * tid + 1];
    int sum2 = h0 + h1;
    part[tid] = sum2;
    __syncthreads();
    for (int off = 1; off < 256; off <<= 1) {
        int u = (tid >= off) ? part[tid - off] : 0;
        __syncthreads();
        part[tid] += u;
        __syncthreads();
    }
    int excl = part[tid] - sum2;
    hist[2 * tid]     = excl;
    hist[2 * tid + 1] = excl + h0;
    __syncthreads();
    int rowbase = b * BUCKROWS;
    for (int i = tid; i < BUCKROWS; i += 256) {
        int g = rowbase + i;
        if (g < N_NODES) rowptr[g] = base + hist[i];
    }
    __syncthreads();
    for (int i = tid; i < cnt; i += 256) {
        int2 cv = cv_in[base + i];
        int pos = atomicAdd(&hist[cv.x >> 18], 1);    // LDS cursor
        cv_out[base + pos] = cv;                      // within 64KB window
    }
}

#define STAGE8(i, VV, RR) { int kk = g + 8 * (i);                            \
    VV = __shfl(my_v, kk, 64);                                               \
    int cc = __shfl(my_c, kk, 64);                                           \
    RR = ((const uint4*)(Eh + (size_t)cc * DIM))[q]; }

// vector consume: 8 bitop-cvt + packed fma
#define CONSV(VV, RR) {                                                      \
    f32x4 X = {bflo(RR.x), bfhi(RR.x), bflo(RR.y), bfhi(RR.y)};              \
    f32x4 Y = {bflo(RR.z), bfhi(RR.z), bflo(RR.w), bfhi(RR.w)};              \
    f32x4 V4 = {VV, VV, VV, VV};                                             \
    A = __builtin_elementwise_fma(V4, X, A);                                 \
    B = __builtin_elementwise_fma(V4, Y, B); }

// scalar consume (partial3f, unchanged from round 11)
#define CONS8(VV, RR) {                                                      \
    a0 += VV * bflo(RR.x); a1 += VV * bfhi(RR.x);                            \
    a2 += VV * bflo(RR.y); a3 += VV * bfhi(RR.y);                            \
    a4 += VV * bflo(RR.z); a5 += VV * bfhi(RR.z);                            \
    a6 += VV * bflo(RR.w); a7 += VV * bfhi(RR.w); }

// ---- SpMM bf16: one wave/row; 8 lanes/edge x 16B; LDS-transpose reduce ----
__global__ void spmm_rows_h(const int* __restrict__ rowptr, const int2* __restrict__ cv,
                            const ushort_t* __restrict__ Eh, ushort_t* __restrict__ EoutH) {
    __shared__ float red[4][8][68];                   // per-wave slab, bank-padded
    int t = blockIdx.x * blockDim.x + threadIdx.x;
    int row = t >> 6;
    if (row >= N_NODES) return;
    int lane = t & 63;
    int g = lane >> 3, q = lane & 7;
    int wid = threadIdx.x >> 6;
    int ru = __builtin_amdgcn_readfirstlane(row);
    int start = rowptr[ru], end = rowptr[ru + 1];
    int len = end - start;
    int nfull = min(len, 64);
    int clampi = (lane < nfull) ? lane : (nfull > 0 ? nfull - 1 : 0);
    int2 mycv = cv[start + clampi];                   // clamped: no over-read
    float my_v = (lane < nfull) ? __int_as_float(mycv.y) : 0.f;
    int my_c = mycv.x & COLMASK;
    f32x4 A = {0.f, 0.f, 0.f, 0.f}, B = {0.f, 0.f, 0.f, 0.f};
    int iters = (nfull + 7) >> 3;                     // wave-uniform
    if (iters > 0) {
        float va, vb, vc; uint4 ra, rb, rc;
        STAGE8(0, va, ra);
        if (iters > 1) STAGE8(1, vb, rb);
        for (int i = 2; i < iters; ++i) {
            STAGE8(i, vc, rc);
            CONSV(va, ra);
            va = vb; ra = rb; vb = vc; rb = rc;
        }
        CONSV(va, ra);
        if (iters > 1) CONSV(vb, rb);
    }
    // rare tail: rows longer than 64 edges
    for (int j = start + 64 + g; j < end; j += 8) {
        int2 c = cv[j];
        float vv = __int_as_float(c.y);
        uint4 rr = ((const uint4*)(Eh + (size_t)(c.x & COLMASK) * DIM))[q];
        CONSV(vv, rr);
    }
    // wave-local LDS transpose reduce (per-wave DS ops are in-order; no barrier)
    float* rb_ = &red[wid][0][0];
    *(f32x4*)(rb_ + g * 68 + q * 8)     = A;
    *(f32x4*)(rb_ + g * 68 + q * 8 + 4) = B;
    __builtin_amdgcn_wave_barrier();
    float s = 0.f;
    #pragma unroll
    for (int gg = 0; gg < 8; ++gg) s += rb_[gg * 68 + lane];
    EoutH[(size_t)row * DIM + lane] = f2bf(s);
}

#define GATHER_BODY                                                          \
    int start = rowptr[ru], end = rowptr[ru + 1];                            \
    int len = end - start;                                                   \
    int nfull = min(len, 64);                                                \
    int2 mycv = cv[start + lane];                                            \
    float my_v = (lane < nfull) ? __int_as_float(mycv.y) : 0.f;              \
    int   my_c = mycv.x & COLMASK;                                           \
    float a0=0,a1=0,a2=0,a3=0,a4=0,a5=0,a6=0,a7=0;                           \
    int iters = (nfull + 7) >> 3;                                            \
    if (iters > 0) {                                                         \
        float va, vb, vc; uint4 ra, rb, rc;                                  \
        STAGE8(0, va, ra);                                                   \
        if (iters > 1) STAGE8(1, vb, rb);                                    \
        for (int i = 2; i < iters; ++i) {                                    \
            STAGE8(i, vc, rc);                                               \
            CONS8(va, ra);                                                   \
            va = vb; ra = rb; vb = vc; rb = rc;                              \
        }                                                                    \
        CONS8(va, ra);                                                       \
        if (iters > 1) CONS8(vb, rb);                                        \
    }                                                                        \
    for (int j = start + 64 + g; j < end; j += 8) {                          \
        int2 c = cv[j];                                                      \
        float vv = __int_as_float(c.y);                                      \
        uint4 rr = ((const uint4*)(Eh + (size_t)(c.x & COLMASK) * DIM))[q];  \
        CONS8(vv, rr);                                                       \
    }                                                                        \
    _Pragma("unroll")                                                        \
    for (int off = 8; off <= 32; off <<= 1) {                                \
        a0 += __shfl_xor(a0, off, 64); a1 += __shfl_xor(a1, off, 64);        \
        a2 += __shfl_xor(a2, off, 64); a3 += __shfl_xor(a3, off, 64);        \
        a4 += __shfl_xor(a4, off, 64); a5 += __shfl_xor(a5, off, 64);        \
        a6 += __shfl_xor(a6, off, 64); a7 += __shfl_xor(a7, off, 64);        \
    }

// ---- partial3f: acc = emb + e0 + e1 + (A*e1) at batch rows ----------------
__global__ void partial3f(const int* __restrict__ rowptr, const int2* __restrict__ cv,
                          const ushort_t* __restrict__ Eh,      // e1
                          const ushort_t* __restrict__ E0h,     // e0
                          const float* __restrict__ emb,
                          const int* __restrict__ U, const int* __restrict__ I,
                          float* __restrict__ accU, float* __restrict__ accI) {
    int t = blockIdx.x * blockDim.x + threadIdx.x;
    int s = t >> 6;
    if (s >= 2 * BATCH) return;
    int lane = t & 63;
    int g = lane >> 3, q = lane & 7;
    int su = __builtin_amdgcn_readfirstlane(s);
    int row;
    float* acc;
    if (su < BATCH) {
        row = U[su];
        acc = accU + (size_t)su * DIM;
    } else {
        row = N_USERS + I[su - BATCH];
        acc = accI + (size_t)(su - BATCH) * DIM;
    }
    int ru = row;
    GATHER_BODY
    if (g == 0) {
        const float4* ef = (const float4*)(emb + (size_t)row * DIM);
        float4 ea = ef[2 * q], eb = ef[2 * q + 1];
        uint4 s0 = ((const uint4*)(E0h + (size_t)row * DIM))[q];
        uint4 s1 = ((const uint4*)(Eh  + (size_t)row * DIM))[q];
        float4 pa, pb;
        pa.x = ea.x + bflo(s0.x) + bflo(s1.x) + a0;
        pa.y = ea.y + bfhi(s0.x) + bfhi(s1.x) + a1;
        pa.z = ea.z + bflo(s0.y) + bflo(s1.y) + a2;
        pa.w = ea.w + bfhi(s0.y) + bfhi(s1.y) + a3;
        pb.x = eb.x + bflo(s0.z) + bflo(s1.z) + a4;
        pb.y = eb.y + bfhi(s0.z) + bfhi(s1.z) + a5;
        pb.z = eb.z + bflo(s0.w) + bflo(s1.w) + a6;
        pb.w = eb.w + bfhi(s0.w) + bfhi(s1.w) + a7;
        ((float4*)acc)[2 * q]     = pa;
        ((float4*)acc)[2 * q + 1] = pb;
    }
}

// ---- final dot, scale 1/16 --------------------------------------------------
__global__ void dot_out(const float* __restrict__ accU, const float* __restrict__ accI,
                        float* __restrict__ out) {
    int t = blockIdx.x * blockDim.x + threadIdx.x;
    int b = t >> 6, lane = t & 63;
    if (b >= BATCH) return;
    float p = accU[(size_t)b * DIM + lane] * accI[(size_t)b * DIM + lane];
    #pragma unroll
    for (int off = 32; off; off >>= 1) p += __shfl_xor(p, off, 64);
    if (lane == 0) out[b] = p * (1.0f / 16.0f);
}

extern "C" void kernel_launch(void* const* d_in, const int* in_sizes, int n_in,
                              void* d_out, int out_size, void* d_ws, size_t ws_size,
                              hipStream_t stream) {
    const float* emb   = (const float*)d_in[0];
    const int*   Arows = (const int*)d_in[1];
    const int*   Acols = (const int*)d_in[2];
    const float* Avals = (const float*)d_in[3];
    const int*   U     = (const int*)d_in[4];
    const int*   I     = (const int*)d_in[5];
    float* out = (float*)d_out;

    char* ws = (char*)d_ws;
    size_t off = 0;
    auto alloc = [&](size_t bytes) {
        char* p = ws + off;
        off += (bytes + 255) & ~(size_t)255;
        return p;
    };
    ushort_t* emb_h  = (ushort_t*)alloc((size_t)N_NODES * DIM * 2);   // 19.2 MB
    ushort_t* e0_h   = (ushort_t*)alloc((size_t)N_NODES * DIM * 2);   // 19.2 MB
    ushort_t* e1_h   = (ushort_t*)alloc((size_t)N_NODES * DIM * 2);   // 19.2 MB
    int2*     colval = (int2*)    alloc(((size_t)NNZ_C + 64) * 8);    // 19.2 MB (row-sorted)
    int2*     cv_tmp = (int2*)    alloc(((size_t)NNZ_C + 64) * 8);    // 19.2 MB (bucket-grouped)
    float*    accU   = (float*)   alloc((size_t)BATCH * DIM * 4);     // 4.2 MB
    float*    accI   = (float*)   alloc((size_t)BATCH * DIM * 4);     // 4.2 MB
    int*      rowptr = (int*)     alloc((size_t)(N_NODES + 1) * 4);   // 0.6 MB
    int*      ghist  = (int*)     alloc((size_t)NBUCK * NCHUNK * 4);  // 344 KB
    int*      btot   = (int*)     alloc((size_t)NBUCK * 4);
    int*      bbase  = (int*)     alloc((size_t)(NBUCK + 1) * 4);

    // ---- build (+ emb->bf16 conv fused with k1) ----
    k1_conv<<<NCHUNK + CONVBLK, 256, 0, stream>>>(Arows, ghist, emb, emb_h);
    k2a_scan_chunks<<<NBUCK, 512, 0, stream>>>(ghist, btot);
    k2b_scan_buckets<<<1, 512, 0, stream>>>(btot, bbase, rowptr);
    k3_scatter<<<NCHUNK, 256, 0, stream>>>(Arows, Acols, Avals, ghist, bbase, cv_tmp);
    k4_sort<<<NBUCK, 256, 0, stream>>>(bbase, cv_tmp, rowptr, colval);

    int spmm_blocks = (N_NODES * 64 + 255) / 256;
    int bacc_blocks = (BATCH * 64 + 255) / 256;
    int p3_blocks   = (2 * BATCH * 64 + 255) / 256;

    // layer 1: emb_h -> e0_h
    spmm_rows_h<<<spmm_blocks, 256, 0, stream>>>(rowptr, colval, emb_h, e0_h);
    // layer 2: e0_h -> e1_h
    spmm_rows_h<<<spmm_blocks, 256, 0, stream>>>(rowptr, colval, e0_h, e1_h);
    // layers 0..3 at batch rows: acc = emb + e0 + e1 + A*e1
    partial3f<<<p3_blocks, 256, 0, stream>>>(rowptr, colval, e1_h, e0_h, emb,
                                             U, I, accU, accI);
    dot_out<<<bacc_blocks, 256, 0, stream>>>(accU, accI, out);
}

// Round 13
// 198.685 us; speedup vs baseline: 1.7693x; 1.0274x over previous
//
#include <hip/hip_runtime.h>

#define N_USERS 100000
#define N_ITEMS 50000
#define N_NODES 150000
#define DIM 64
#define NNZ_C 2400000
#define BATCH 16384

#define BUCKROWS 512
#define NBUCK ((N_NODES + BUCKROWS - 1) / BUCKROWS)   // 293 buckets of 512 rows
#define CHUNK 8192
#define NCHUNK ((NNZ_C + CHUNK - 1) / CHUNK)          // 293 chunks
#define COLMASK 0x3FFFF                                // 18 bits for col
#define CONVBLK ((N_NODES * DIM / 4 + 255) / 256)      // 9375

typedef unsigned short ushort_t;
typedef float f32x4 __attribute__((ext_vector_type(4)));

__device__ inline unsigned short f2bf(float f) {      // round-to-nearest-even
    unsigned int b = __float_as_uint(f);
    unsigned int r = (b + 0x7FFFu + ((b >> 16) & 1u)) >> 16;
    return (unsigned short)r;
}
__device__ inline float bflo(unsigned int u) { return __uint_as_float(u << 16); }
__device__ inline float bfhi(unsigned int u) { return __uint_as_float(u & 0xFFFF0000u); }

// ---- fused: k1 chunk-histogram (blocks 0..NCHUNK) + emb->bf16 conv --------
__global__ void k1_conv(const int* __restrict__ rows, int* __restrict__ ghist,
                        const float* __restrict__ emb, ushort_t* __restrict__ embh) {
    __shared__ int hist[NBUCK];
    int blk = blockIdx.x, tid = threadIdx.x;
    if (blk < NCHUNK) {
        for (int b = tid; b < NBUCK; b += 256) hist[b] = 0;
        __syncthreads();
        int base = blk * CHUNK;
        int end = min(base + CHUNK, NNZ_C);
        for (int e = base + tid; e < end; e += 256)
            atomicAdd(&hist[rows[e] >> 9], 1);        // LDS atomic
        __syncthreads();
        for (int b = tid; b < NBUCK; b += 256)
            ghist[(size_t)b * NCHUNK + blk] = hist[b];
    } else {
        int i = (blk - NCHUNK) * 256 + tid;           // 4 elems/thread
        if (i < N_NODES * DIM / 4) {
            float4 v = ((const float4*)emb)[i];
            ushort4 h;
            h.x = f2bf(v.x); h.y = f2bf(v.y); h.z = f2bf(v.z); h.w = f2bf(v.w);
            ((ushort4*)embh)[i] = h;
        }
    }
}

// ---- k2a: per-bucket exclusive scan over NCHUNK (293) entries --------------
__global__ void k2a_scan_chunks(int* __restrict__ ghist, int* __restrict__ btot) {
    __shared__ int s[512];
    int b = blockIdx.x, t = threadIdx.x;
    int v = (t < NCHUNK) ? ghist[(size_t)b * NCHUNK + t] : 0;
    s[t] = v;
    __syncthreads();
    for (int off = 1; off < 512; off <<= 1) {
        int u = (t >= off) ? s[t - off] : 0;
        __syncthreads();
        s[t] += u;
        __syncthreads();
    }
    if (t < NCHUNK) ghist[(size_t)b * NCHUNK + t] = s[t] - v;
    if (t == NCHUNK - 1) btot[b] = s[t];
}

// ---- k2b: exclusive scan of 293 bucket totals ------------------------------
__global__ void k2b_scan_buckets(const int* __restrict__ btot, int* __restrict__ bbase,
                                 int* __restrict__ rowptr) {
    __shared__ int s[512];
    int t = threadIdx.x;
    int v = (t < NBUCK) ? btot[t] : 0;
    s[t] = v;
    __syncthreads();
    for (int off = 1; off < 512; off <<= 1) {
        int u = (t >= off) ? s[t - off] : 0;
        __syncthreads();
        s[t] += u;
        __syncthreads();
    }
    if (t < NBUCK) bbase[t] = s[t] - v;
    if (t == 511) { bbase[NBUCK] = s[511]; rowptr[N_NODES] = NNZ_C; }
}

// ---- k3: scatter edges into bucket order; 1024 thr/block for occupancy ----
__global__ void k3_scatter(const int* __restrict__ rows, const int* __restrict__ cols,
                           const float* __restrict__ vals,
                           const int* __restrict__ ghist, const int* __restrict__ bbase,
                           int2* __restrict__ cv_tmp) {
    __shared__ int cur[NBUCK];
    int blk = blockIdx.x, tid = threadIdx.x;
    for (int b = tid; b < NBUCK; b += 1024)
        cur[b] = bbase[b] + ghist[(size_t)b * NCHUNK + blk];
    __syncthreads();
    int base = blk * CHUNK;
    int end = min(base + CHUNK, NNZ_C);
    for (int e = base + tid; e < end; e += 1024) {
        int r = rows[e];
        int pos = atomicAdd(&cur[r >> 9], 1);         // LDS atomic
        int2 cv;
        cv.x = ((r & 511) << 18) | cols[e];           // packed rl|col
        cv.y = __float_as_int(vals[e]);
        cv_tmp[pos] = cv;
    }
}

// ---- k4: sort 512 row-locals per bucket; 512 thr = 1 row-local/thread -----
__global__ void k4_sort(const int* __restrict__ bbase,
                        const int2* __restrict__ cv_in,
                        int* __restrict__ rowptr, int2* __restrict__ cv_out) {
    __shared__ int hist[BUCKROWS];
    __shared__ int s[BUCKROWS];
    int b = blockIdx.x, tid = threadIdx.x;
    int base = bbase[b];
    int cnt = bbase[b + 1] - base;
    hist[tid] = 0;
    __syncthreads();
    for (int i = tid; i < cnt; i += 512)
        atomicAdd(&hist[cv_in[base + i].x >> 18], 1);
    __syncthreads();
    int h = hist[tid];
    s[tid] = h;
    __syncthreads();
    for (int off = 1; off < 512; off <<= 1) {
        int u = (tid >= off) ? s[tid - off] : 0;
        __syncthreads();
        s[tid] += u;
        __syncthreads();
    }
    int excl = s[tid] - h;
    int g = b * BUCKROWS + tid;
    if (g < N_NODES) rowptr[g] = base + excl;
    hist[tid] = excl;                                 // becomes cursor
    __syncthreads();
    for (int i = tid; i < cnt; i += 512) {
        int2 cv = cv_in[base + i];
        int pos = atomicAdd(&hist[cv.x >> 18], 1);    // LDS cursor
        cv_out[base + pos] = cv;                      // within 64KB window
    }
}

#define STAGE8(i, VV, RR) { int kk = g + 8 * (i);                            \
    VV = __shfl(my_v, kk, 64);                                               \
    int cc = __shfl(my_c, kk, 64);                                           \
    RR = ((const uint4*)(Eh + (size_t)cc * DIM))[q]; }

// vector consume: 8 bitop-cvt + packed fma
#define CONSV(VV, RR) {                                                      \
    f32x4 X = {bflo(RR.x), bfhi(RR.x), bflo(RR.y), bfhi(RR.y)};              \
    f32x4 Y = {bflo(RR.z), bfhi(RR.z), bflo(RR.w), bfhi(RR.w)};              \
    f32x4 V4 = {VV, VV, VV, VV};                                             \
    A = __builtin_elementwise_fma(V4, X, A);                                 \
    B = __builtin_elementwise_fma(V4, Y, B); }

// scalar consume (partial3f)
#define CONS8(VV, RR) {                                                      \
    a0 += VV * bflo(RR.x); a1 += VV * bfhi(RR.x);                            \
    a2 += VV * bflo(RR.y); a3 += VV * bfhi(RR.y);                            \
    a4 += VV * bflo(RR.z); a5 += VV * bfhi(RR.z);                            \
    a6 += VV * bflo(RR.w); a7 += VV * bfhi(RR.w); }

// ---- SpMM bf16: one wave/row; 8 lanes/edge x 16B; LDS-transpose reduce ----
__global__ void spmm_rows_h(const int* __restrict__ rowptr, const int2* __restrict__ cv,
                            const ushort_t* __restrict__ Eh, ushort_t* __restrict__ EoutH) {
    __shared__ float red[4][8][68];                   // per-wave slab, bank-padded
    int t = blockIdx.x * blockDim.x + threadIdx.x;
    int row = t >> 6;
    if (row >= N_NODES) return;
    int lane = t & 63;
    int g = lane >> 3, q = lane & 7;
    int wid = threadIdx.x >> 6;
    int ru = __builtin_amdgcn_readfirstlane(row);
    int start = rowptr[ru], end = rowptr[ru + 1];
    int len = end - start;
    int nfull = min(len, 64);
    int clampi = (lane < nfull) ? lane : (nfull > 0 ? nfull - 1 : 0);
    int2 mycv = cv[start + clampi];                   // clamped: no over-read
    float my_v = (lane < nfull) ? __int_as_float(mycv.y) : 0.f;
    int my_c = mycv.x & COLMASK;
    f32x4 A = {0.f, 0.f, 0.f, 0.f}, B = {0.f, 0.f, 0.f, 0.f};
    int iters = (nfull + 7) >> 3;                     // wave-uniform
    if (iters > 0) {
        float va, vb, vc; uint4 ra, rb, rc;
        STAGE8(0, va, ra);
        if (iters > 1) STAGE8(1, vb, rb);
        for (int i = 2; i < iters; ++i) {
            STAGE8(i, vc, rc);
            CONSV(va, ra);
            va = vb; ra = rb; vb = vc; rb = rc;
        }
        CONSV(va, ra);
        if (iters > 1) CONSV(vb, rb);
    }
    // rare tail: rows longer than 64 edges
    for (int j = start + 64 + g; j < end; j += 8) {
        int2 c = cv[j];
        float vv = __int_as_float(c.y);
        uint4 rr = ((const uint4*)(Eh + (size_t)(c.x & COLMASK) * DIM))[q];
        CONSV(vv, rr);
    }
    // wave-local LDS transpose reduce (per-wave DS ops are in-order; no barrier)
    float* rb_ = &red[wid][0][0];
    *(f32x4*)(rb_ + g * 68 + q * 8)     = A;
    *(f32x4*)(rb_ + g * 68 + q * 8 + 4) = B;
    __builtin_amdgcn_wave_barrier();
    float s = 0.f;
    #pragma unroll
    for (int gg = 0; gg < 8; ++gg) s += rb_[gg * 68 + lane];
    EoutH[(size_t)row * DIM + lane] = f2bf(s);
}

#define GATHER_BODY                                                          \
    int start = rowptr[ru], end = rowptr[ru + 1];                            \
    int len = end - start;                                                   \
    int nfull = min(len, 64);                                                \
    int2 mycv = cv[start + lane];                                            \
    float my_v = (lane < nfull) ? __int_as_float(mycv.y) : 0.f;              \
    int   my_c = mycv.x & COLMASK;                                           \
    float a0=0,a1=0,a2=0,a3=0,a4=0,a5=0,a6=0,a7=0;                           \
    int iters = (nfull + 7) >> 3;                                            \
    if (iters > 0) {                                                         \
        float va, vb, vc; uint4 ra, rb, rc;                                  \
        STAGE8(0, va, ra);                                                   \
        if (iters > 1) STAGE8(1, vb, rb);                                    \
        for (int i = 2; i < iters; ++i) {                                    \
            STAGE8(i, vc, rc);                                               \
            CONS8(va, ra);                                                   \
            va = vb; ra = rb; vb = vc; rb = rc;                              \
        }                                                                    \
        CONS8(va, ra);                                                       \
        if (iters > 1) CONS8(vb, rb);                                        \
    }                                                                        \
    for (int j = start + 64 + g; j < end; j += 8) {                          \
        int2 c = cv[j];                                                      \
        float vv = __int_as_float(c.y);                                      \
        uint4 rr = ((const uint4*)(Eh + (size_t)(c.x & COLMASK) * DIM))[q];  \
        CONS8(vv, rr);                                                       \
    }                                                                        \
    _Pragma("unroll")                                                        \
    for (int off = 8; off <= 32; off <<= 1) {                                \
        a0 += __shfl_xor(a0, off, 64); a1 += __shfl_xor(a1, off, 64);        \
        a2 += __shfl_xor(a2, off, 64); a3 += __shfl_xor(a3, off, 64);        \
        a4 += __shfl_xor(a4, off, 64); a5 += __shfl_xor(a5, off, 64);        \
        a6 += __shfl_xor(a6, off, 64); a7 += __shfl_xor(a7, off, 64);        \
    }

// ---- partial3f: acc = emb + e0 + e1 + (A*e1) at batch rows ----------------
__global__ void partial3f(const int* __restrict__ rowptr, const int2* __restrict__ cv,
                          const ushort_t* __restrict__ Eh,      // e1
                          const ushort_t* __restrict__ E0h,     // e0
                          const float* __restrict__ emb,
                          const int* __restrict__ U, const int* __restrict__ I,
                          float* __restrict__ accU, float* __restrict__ accI) {
    int t = blockIdx.x * blockDim.x + threadIdx.x;
    int s = t >> 6;
    if (s >= 2 * BATCH) return;
    int lane = t & 63;
    int g = lane >> 3, q = lane & 7;
    int su = __builtin_amdgcn_readfirstlane(s);
    int row;
    float* acc;
    if (su < BATCH) {
        row = U[su];
        acc = accU + (size_t)su * DIM;
    } else {
        row = N_USERS + I[su - BATCH];
        acc = accI + (size_t)(su - BATCH) * DIM;
    }
    int ru = row;
    GATHER_BODY
    if (g == 0) {
        const float4* ef = (const float4*)(emb + (size_t)row * DIM);
        float4 ea = ef[2 * q], eb = ef[2 * q + 1];
        uint4 s0 = ((const uint4*)(E0h + (size_t)row * DIM))[q];
        uint4 s1 = ((const uint4*)(Eh  + (size_t)row * DIM))[q];
        float4 pa, pb;
        pa.x = ea.x + bflo(s0.x) + bflo(s1.x) + a0;
        pa.y = ea.y + bfhi(s0.x) + bfhi(s1.x) + a1;
        pa.z = ea.z + bflo(s0.y) + bflo(s1.y) + a2;
        pa.w = ea.w + bfhi(s0.y) + bfhi(s1.y) + a3;
        pb.x = eb.x + bflo(s0.z) + bflo(s1.z) + a4;
        pb.y = eb.y + bfhi(s0.z) + bfhi(s1.z) + a5;
        pb.z = eb.z + bflo(s0.w) + bflo(s1.w) + a6;
        pb.w = eb.w + bfhi(s0.w) + bfhi(s1.w) + a7;
        ((float4*)acc)[2 * q]     = pa;
        ((float4*)acc)[2 * q + 1] = pb;
    }
}

// ---- final dot, scale 1/16 --------------------------------------------------
__global__ void dot_out(const float* __restrict__ accU, const float* __restrict__ accI,
                        float* __restrict__ out) {
    int t = blockIdx.x * blockDim.x + threadIdx.x;
    int b = t >> 6, lane = t & 63;
    if (b >= BATCH) return;
    float p = accU[(size_t)b * DIM + lane] * accI[(size_t)b * DIM + lane];
    #pragma unroll
    for (int off = 32; off; off >>= 1) p += __shfl_xor(p, off, 64);
    if (lane == 0) out[b] = p * (1.0f / 16.0f);
}

extern "C" void kernel_launch(void* const* d_in, const int* in_sizes, int n_in,
                              void* d_out, int out_size, void* d_ws, size_t ws_size,
                              hipStream_t stream) {
    const float* emb   = (const float*)d_in[0];
    const int*   Arows = (const int*)d_in[1];
    const int*   Acols = (const int*)d_in[2];
    const float* Avals = (const float*)d_in[3];
    const int*   U     = (const int*)d_in[4];
    const int*   I     = (const int*)d_in[5];
    float* out = (float*)d_out;

    char* ws = (char*)d_ws;
    size_t off = 0;
    auto alloc = [&](size_t bytes) {
        char* p = ws + off;
        off += (bytes + 255) & ~(size_t)255;
        return p;
    };
    ushort_t* emb_h  = (ushort_t*)alloc((size_t)N_NODES * DIM * 2);   // 19.2 MB
    ushort_t* e0_h   = (ushort_t*)alloc((size_t)N_NODES * DIM * 2);   // 19.2 MB
    ushort_t* e1_h   = (ushort_t*)alloc((size_t)N_NODES * DIM * 2);   // 19.2 MB
    int2*     colval = (int2*)    alloc(((size_t)NNZ_C + 64) * 8);    // 19.2 MB (row-sorted)
    int2*     cv_tmp = (int2*)    alloc(((size_t)NNZ_C + 64) * 8);    // 19.2 MB (bucket-grouped)
    float*    accU   = (float*)   alloc((size_t)BATCH * DIM * 4);     // 4.2 MB
    float*    accI   = (float*)   alloc((size_t)BATCH * DIM * 4);     // 4.2 MB
    int*      rowptr = (int*)     alloc((size_t)(N_NODES + 1) * 4);   // 0.6 MB
    int*      ghist  = (int*)     alloc((size_t)NBUCK * NCHUNK * 4);  // 344 KB
    int*      btot   = (int*)     alloc((size_t)NBUCK * 4);
    int*      bbase  = (int*)     alloc((size_t)(NBUCK + 1) * 4);

    // ---- build (+ emb->bf16 conv fused with k1) ----
    k1_conv<<<NCHUNK + CONVBLK, 256, 0, stream>>>(Arows, ghist, emb, emb_h);
    k2a_scan_chunks<<<NBUCK, 512, 0, stream>>>(ghist, btot);
    k2b_scan_buckets<<<1, 512, 0, stream>>>(btot, bbase, rowptr);
    k3_scatter<<<NCHUNK, 1024, 0, stream>>>(Arows, Acols, Avals, ghist, bbase, cv_tmp);
    k4_sort<<<NBUCK, 512, 0, stream>>>(bbase, cv_tmp, rowptr, colval);

    int spmm_blocks = (N_NODES * 64 + 255) / 256;
    int bacc_blocks = (BATCH * 64 + 255) / 256;
    int p3_blocks   = (2 * BATCH * 64 + 255) / 256;

    // layer 1: emb_h -> e0_h
    spmm_rows_h<<<spmm_blocks, 256, 0, stream>>>(rowptr, colval, emb_h, e0_h);
    // layer 2: e0_h -> e1_h
    spmm_rows_h<<<spmm_blocks, 256, 0, stream>>>(rowptr, colval, e0_h, e1_h);
    // layers 0..3 at batch rows: acc = emb + e0 + e1 + A*e1
    partial3f<<<p3_blocks, 256, 0, stream>>>(rowptr, colval, e1_h, e0_h, emb,
                                             U, I, accU, accI);
    dot_out<<<bacc_blocks, 256, 0, stream>>>(accU, accI, out);
}

// Round 14
// 189.450 us; speedup vs baseline: 1.8556x; 1.0487x over previous
//
#include <hip/hip_runtime.h>

#define N_USERS 100000
#define N_ITEMS 50000
#define N_NODES 150000
#define DIM 64
#define NNZ_C 2400000
#define BATCH 16384

#define BUCKROWS 512
#define NBUCK ((N_NODES + BUCKROWS - 1) / BUCKROWS)   // 293 buckets of 512 rows
#define CHUNK 8192
#define NCHUNK ((NNZ_C + CHUNK - 1) / CHUNK)          // 293 chunks
#define COLMASK 0x3FFFF                                // 18 bits for col
#define CONVBLK ((N_NODES * DIM / 4 + 255) / 256)      // 9375

typedef unsigned short ushort_t;
typedef float f32x4 __attribute__((ext_vector_type(4)));

__device__ inline unsigned short f2bf(float f) {      // round-to-nearest-even
    unsigned int b = __float_as_uint(f);
    unsigned int r = (b + 0x7FFFu + ((b >> 16) & 1u)) >> 16;
    return (unsigned short)r;
}
__device__ inline float bflo(unsigned int u) { return __uint_as_float(u << 16); }
__device__ inline float bfhi(unsigned int u) { return __uint_as_float(u & 0xFFFF0000u); }

// ---- fused: k1 chunk-histogram (blocks 0..NCHUNK) + emb->bf16 conv --------
__global__ void k1_conv(const int* __restrict__ rows, int* __restrict__ ghist,
                        const float* __restrict__ emb, ushort_t* __restrict__ embh) {
    __shared__ int hist[NBUCK];
    int blk = blockIdx.x, tid = threadIdx.x;
    if (blk < NCHUNK) {
        for (int b = tid; b < NBUCK; b += 256) hist[b] = 0;
        __syncthreads();
        int base = blk * CHUNK;
        int end = min(base + CHUNK, NNZ_C);
        for (int e = base + tid; e < end; e += 256)
            atomicAdd(&hist[rows[e] >> 9], 1);        // LDS atomic
        __syncthreads();
        for (int b = tid; b < NBUCK; b += 256)
            ghist[(size_t)b * NCHUNK + blk] = hist[b];
    } else {
        int i = (blk - NCHUNK) * 256 + tid;           // 4 elems/thread
        if (i < N_NODES * DIM / 4) {
            float4 v = ((const float4*)emb)[i];
            ushort4 h;
            h.x = f2bf(v.x); h.y = f2bf(v.y); h.z = f2bf(v.z); h.w = f2bf(v.w);
            ((ushort4*)embh)[i] = h;
        }
    }
}

// ---- k2a: per-bucket exclusive scan over NCHUNK (293) entries --------------
__global__ void k2a_scan_chunks(int* __restrict__ ghist, int* __restrict__ btot) {
    __shared__ int s[512];
    int b = blockIdx.x, t = threadIdx.x;
    int v = (t < NCHUNK) ? ghist[(size_t)b * NCHUNK + t] : 0;
    s[t] = v;
    __syncthreads();
    for (int off = 1; off < 512; off <<= 1) {
        int u = (t >= off) ? s[t - off] : 0;
        __syncthreads();
        s[t] += u;
        __syncthreads();
    }
    if (t < NCHUNK) ghist[(size_t)b * NCHUNK + t] = s[t] - v;
    if (t == NCHUNK - 1) btot[b] = s[t];
}

// ---- k2b: exclusive scan of 293 bucket totals ------------------------------
__global__ void k2b_scan_buckets(const int* __restrict__ btot, int* __restrict__ bbase,
                                 int* __restrict__ rowptr) {
    __shared__ int s[512];
    int t = threadIdx.x;
    int v = (t < NBUCK) ? btot[t] : 0;
    s[t] = v;
    __syncthreads();
    for (int off = 1; off < 512; off <<= 1) {
        int u = (t >= off) ? s[t - off] : 0;
        __syncthreads();
        s[t] += u;
        __syncthreads();
    }
    if (t < NBUCK) bbase[t] = s[t] - v;
    if (t == 511) { bbase[NBUCK] = s[511]; rowptr[N_NODES] = NNZ_C; }
}

// ---- k3: scatter edges into bucket order; 1024 thr/block for occupancy ----
__global__ void k3_scatter(const int* __restrict__ rows, const int* __restrict__ cols,
                           const float* __restrict__ vals,
                           const int* __restrict__ ghist, const int* __restrict__ bbase,
                           int2* __restrict__ cv_tmp) {
    __shared__ int cur[NBUCK];
    int blk = blockIdx.x, tid = threadIdx.x;
    for (int b = tid; b < NBUCK; b += 1024)
        cur[b] = bbase[b] + ghist[(size_t)b * NCHUNK + blk];
    __syncthreads();
    int base = blk * CHUNK;
    int end = min(base + CHUNK, NNZ_C);
    for (int e = base + tid; e < end; e += 1024) {
        int r = rows[e];
        int pos = atomicAdd(&cur[r >> 9], 1);         // LDS atomic
        int2 cv;
        cv.x = ((r & 511) << 18) | cols[e];           // packed rl|col
        cv.y = __float_as_int(vals[e]);
        cv_tmp[pos] = cv;
    }
}

// ---- k4: sort 512 row-locals per bucket; 512 thr = 1 row-local/thread -----
__global__ void k4_sort(const int* __restrict__ bbase,
                        const int2* __restrict__ cv_in,
                        int* __restrict__ rowptr, int2* __restrict__ cv_out) {
    __shared__ int hist[BUCKROWS];
    __shared__ int s[BUCKROWS];
    int b = blockIdx.x, tid = threadIdx.x;
    int base = bbase[b];
    int cnt = bbase[b + 1] - base;
    hist[tid] = 0;
    __syncthreads();
    for (int i = tid; i < cnt; i += 512)
        atomicAdd(&hist[cv_in[base + i].x >> 18], 1);
    __syncthreads();
    int h = hist[tid];
    s[tid] = h;
    __syncthreads();
    for (int off = 1; off < 512; off <<= 1) {
        int u = (tid >= off) ? s[tid - off] : 0;
        __syncthreads();
        s[tid] += u;
        __syncthreads();
    }
    int excl = s[tid] - h;
    int g = b * BUCKROWS + tid;
    if (g < N_NODES) rowptr[g] = base + excl;
    hist[tid] = excl;                                 // becomes cursor
    __syncthreads();
    for (int i = tid; i < cnt; i += 512) {
        int2 cv = cv_in[base + i];
        int pos = atomicAdd(&hist[cv.x >> 18], 1);    // LDS cursor
        cv_out[base + pos] = cv;                      // within 64KB window
    }
}

#define STAGE8(i, VV, RR) { int kk = g + 8 * (i);                            \
    VV = __shfl(my_v, kk, 64);                                               \
    int cc = __shfl(my_c, kk, 64);                                           \
    RR = ((const uint4*)(Eh + (size_t)cc * DIM))[q]; }

#define CONSV(VV, RR) {                                                      \
    f32x4 X = {bflo(RR.x), bfhi(RR.x), bflo(RR.y), bfhi(RR.y)};              \
    f32x4 Y = {bflo(RR.z), bfhi(RR.z), bflo(RR.w), bfhi(RR.w)};              \
    f32x4 V4 = {VV, VV, VV, VV};                                             \
    A = __builtin_elementwise_fma(V4, X, A);                                 \
    B = __builtin_elementwise_fma(V4, Y, B); }

// Gather one row of A*Eh (8 lanes/edge, depth-3 pipeline) then LDS-transpose
// reduce so lane=dim holds the row's dim-sum. Per-wave DS ops are in-order.
#define ROW_GATHER_REDUCE(ROWV, SOUT) {                                      \
    int start = rowptr[ROWV], end = rowptr[(ROWV) + 1];                      \
    int len = end - start;                                                   \
    int nfull = min(len, 64);                                                \
    int clampi = (lane < nfull) ? lane : (nfull > 0 ? nfull - 1 : 0);        \
    int2 mycv = cv[start + clampi];                                          \
    float my_v = (lane < nfull) ? __int_as_float(mycv.y) : 0.f;              \
    int my_c = mycv.x & COLMASK;                                             \
    f32x4 A = {0.f,0.f,0.f,0.f}, B = {0.f,0.f,0.f,0.f};                      \
    int iters = (nfull + 7) >> 3;                                            \
    if (iters > 0) {                                                         \
        float va, vb, vc; uint4 ra, rb, rc;                                  \
        STAGE8(0, va, ra);                                                   \
        if (iters > 1) STAGE8(1, vb, rb);                                    \
        for (int i = 2; i < iters; ++i) {                                    \
            STAGE8(i, vc, rc);                                               \
            CONSV(va, ra);                                                   \
            va = vb; ra = rb; vb = vc; rb = rc;                              \
        }                                                                    \
        CONSV(va, ra);                                                       \
        if (iters > 1) CONSV(vb, rb);                                        \
    }                                                                        \
    for (int j = start + 64 + g; j < end; j += 8) {                          \
        int2 c = cv[j];                                                      \
        float vv = __int_as_float(c.y);                                      \
        uint4 rr = ((const uint4*)(Eh + (size_t)(c.x & COLMASK) * DIM))[q];  \
        CONSV(vv, rr);                                                       \
    }                                                                        \
    __builtin_amdgcn_wave_barrier();                                         \
    *(f32x4*)(rb_ + g * 68 + q * 8)     = A;                                 \
    *(f32x4*)(rb_ + g * 68 + q * 8 + 4) = B;                                 \
    __builtin_amdgcn_wave_barrier();                                         \
    SOUT = 0.f;                                                              \
    _Pragma("unroll")                                                        \
    for (int gg = 0; gg < 8; ++gg) SOUT += rb_[gg * 68 + lane];              \
    __builtin_amdgcn_wave_barrier();                                         \
}

// ---- SpMM bf16: one wave/row ----------------------------------------------
__global__ void spmm_rows_h(const int* __restrict__ rowptr, const int2* __restrict__ cv,
                            const ushort_t* __restrict__ Eh, ushort_t* __restrict__ EoutH) {
    __shared__ float red[4][8][68];                   // per-wave slab, bank-padded
    int t = blockIdx.x * blockDim.x + threadIdx.x;
    int row = t >> 6;
    if (row >= N_NODES) return;
    int lane = t & 63;
    int g = lane >> 3, q = lane & 7;
    float* rb_ = &red[threadIdx.x >> 6][0][0];
    int ru = __builtin_amdgcn_readfirstlane(row);
    float s;
    ROW_GATHER_REDUCE(ru, s)
    EoutH[(size_t)row * DIM + lane] = f2bf(s);
}

// ---- pair3_dot: one wave per (U,I) pair; 4-layer sums for both rows + dot -
__global__ void pair3_dot(const int* __restrict__ rowptr, const int2* __restrict__ cv,
                          const ushort_t* __restrict__ Eh,      // e1
                          const ushort_t* __restrict__ E0h,     // e0
                          const float* __restrict__ emb,
                          const int* __restrict__ U, const int* __restrict__ I,
                          float* __restrict__ out) {
    __shared__ float red[4][8][68];
    int t = blockIdx.x * blockDim.x + threadIdx.x;
    int b = t >> 6;
    if (b >= BATCH) return;
    int lane = t & 63;
    int g = lane >> 3, q = lane & 7;
    float* rb_ = &red[threadIdx.x >> 6][0][0];
    int bu = __builtin_amdgcn_readfirstlane(b);
    int urow = U[bu];
    int irow = N_USERS + I[bu];

    float su, si;
    ROW_GATHER_REDUCE(urow, su)
    ROW_GATHER_REDUCE(irow, si)

    // self terms: emb(f32) + e0 + e1, per-lane (lane = dim), coalesced
    su += emb[(size_t)urow * DIM + lane]
        + bflo((unsigned)E0h[(size_t)urow * DIM + lane])
        + bflo((unsigned)Eh [(size_t)urow * DIM + lane]);
    si += emb[(size_t)irow * DIM + lane]
        + bflo((unsigned)E0h[(size_t)irow * DIM + lane])
        + bflo((unsigned)Eh [(size_t)irow * DIM + lane]);

    float p = su * si;
    #pragma unroll
    for (int off = 32; off; off >>= 1) p += __shfl_xor(p, off, 64);
    if (lane == 0) out[b] = p * (1.0f / 16.0f);
}

extern "C" void kernel_launch(void* const* d_in, const int* in_sizes, int n_in,
                              void* d_out, int out_size, void* d_ws, size_t ws_size,
                              hipStream_t stream) {
    const float* emb   = (const float*)d_in[0];
    const int*   Arows = (const int*)d_in[1];
    const int*   Acols = (const int*)d_in[2];
    const float* Avals = (const float*)d_in[3];
    const int*   U     = (const int*)d_in[4];
    const int*   I     = (const int*)d_in[5];
    float* out = (float*)d_out;

    char* ws = (char*)d_ws;
    size_t off = 0;
    auto alloc = [&](size_t bytes) {
        char* p = ws + off;
        off += (bytes + 255) & ~(size_t)255;
        return p;
    };
    ushort_t* emb_h  = (ushort_t*)alloc((size_t)N_NODES * DIM * 2);   // 19.2 MB
    ushort_t* e0_h   = (ushort_t*)alloc((size_t)N_NODES * DIM * 2);   // 19.2 MB
    ushort_t* e1_h   = (ushort_t*)alloc((size_t)N_NODES * DIM * 2);   // 19.2 MB
    int2*     colval = (int2*)    alloc(((size_t)NNZ_C + 64) * 8);    // 19.2 MB (row-sorted)
    int2*     cv_tmp = (int2*)    alloc(((size_t)NNZ_C + 64) * 8);    // 19.2 MB (bucket-grouped)
    int*      rowptr = (int*)     alloc((size_t)(N_NODES + 1) * 4);   // 0.6 MB
    int*      ghist  = (int*)     alloc((size_t)NBUCK * NCHUNK * 4);  // 344 KB
    int*      btot   = (int*)     alloc((size_t)NBUCK * 4);
    int*      bbase  = (int*)     alloc((size_t)(NBUCK + 1) * 4);

    // ---- build (+ emb->bf16 conv fused with k1) ----
    k1_conv<<<NCHUNK + CONVBLK, 256, 0, stream>>>(Arows, ghist, emb, emb_h);
    k2a_scan_chunks<<<NBUCK, 512, 0, stream>>>(ghist, btot);
    k2b_scan_buckets<<<1, 512, 0, stream>>>(btot, bbase, rowptr);
    k3_scatter<<<NCHUNK, 1024, 0, stream>>>(Arows, Acols, Avals, ghist, bbase, cv_tmp);
    k4_sort<<<NBUCK, 512, 0, stream>>>(bbase, cv_tmp, rowptr, colval);

    int spmm_blocks = (N_NODES * 64 + 255) / 256;
    int pair_blocks = (BATCH * 64 + 255) / 256;

    // layer 1: emb_h -> e0_h
    spmm_rows_h<<<spmm_blocks, 256, 0, stream>>>(rowptr, colval, emb_h, e0_h);
    // layer 2: e0_h -> e1_h
    spmm_rows_h<<<spmm_blocks, 256, 0, stream>>>(rowptr, colval, e0_h, e1_h);
    // fused epilogue: both rows' 4-layer sums + dot, one wave per pair
    pair3_dot<<<pair_blocks, 256, 0, stream>>>(rowptr, colval, e1_h, e0_h, emb,
                                               U, I, out);
}